// Round 1
// baseline (946.601 us; speedup 1.0000x reference)
//
#include <hip/hip_runtime.h>
#include <math.h>

#define N_NODES 50000
#define E_EDGES 800000
#define ET (E_EDGES + N_NODES)   // edges + self loops = 850000
#define NBLK_SCAN ((N_NODES + 255) / 256)   // 196

// ---------------- CSR build ----------------

__global__ void zero_int_kernel(int* __restrict__ p, int n) {
    int i = blockIdx.x * blockDim.x + threadIdx.x;
    if (i < n) p[i] = 0;
}

__global__ void hist_kernel(const int* __restrict__ ei, int* __restrict__ cnt) {
    int e = blockIdx.x * blockDim.x + threadIdx.x;
    if (e < ET) {
        int d = (e < E_EDGES) ? ei[E_EDGES + e] : (e - E_EDGES);
        atomicAdd(&cnt[d], 1);
    }
}

__global__ void scan1_kernel(const int* __restrict__ cnt, int* __restrict__ rp,
                             int* __restrict__ bsum) {
    __shared__ int s[256];
    int i = blockIdx.x * 256 + threadIdx.x;
    int v = (i < N_NODES) ? cnt[i] : 0;
    s[threadIdx.x] = v;
    __syncthreads();
    for (int off = 1; off < 256; off <<= 1) {
        int t = (threadIdx.x >= off) ? s[threadIdx.x - off] : 0;
        __syncthreads();
        s[threadIdx.x] += t;
        __syncthreads();
    }
    if (i < N_NODES) rp[i + 1] = s[threadIdx.x];
    if (threadIdx.x == 255) bsum[blockIdx.x] = s[255];
}

__global__ void scan2_kernel(int* __restrict__ bsum, int nb) {
    __shared__ int s[256];
    int v = (threadIdx.x < nb) ? bsum[threadIdx.x] : 0;
    s[threadIdx.x] = v;
    __syncthreads();
    for (int off = 1; off < 256; off <<= 1) {
        int t = (threadIdx.x >= off) ? s[threadIdx.x - off] : 0;
        __syncthreads();
        s[threadIdx.x] += t;
        __syncthreads();
    }
    if (threadIdx.x < nb) bsum[threadIdx.x] = (threadIdx.x == 0) ? 0 : s[threadIdx.x - 1];
}

// rp[i+1] += block offset (inclusive scan finalize), rp[0]=0,
// cursor[i] = exclusive start (incl - count)
__global__ void scan3_kernel(int* __restrict__ rp, const int* __restrict__ bsum,
                             int* __restrict__ cursor) {
    int i = blockIdx.x * 256 + threadIdx.x;
    if (i == 0) rp[0] = 0;
    if (i < N_NODES) {
        int incl = rp[i + 1] + bsum[i >> 8];
        rp[i + 1] = incl;
        cursor[i] = incl - cursor[i];
    }
}

__global__ void fill_kernel(const int* __restrict__ ei, int* __restrict__ cursor,
                            int* __restrict__ col) {
    int e = blockIdx.x * blockDim.x + threadIdx.x;
    if (e < ET) {
        int s_, d;
        if (e < E_EDGES) { s_ = ei[e]; d = ei[E_EDGES + e]; }
        else             { s_ = e - E_EDGES; d = s_; }
        int p = atomicAdd(&cursor[d], 1);
        col[p] = s_;
    }
}

// ---------------- dense GEMM: C[M,Nd] = A[M,K] @ B[K,Nd] ----------------
// BM=64, BN=32*TN, BK=16, 256 threads, each thread 8 rows x TN cols.

template <int TN>
__global__ __launch_bounds__(256) void gemm_kernel(
        const float* __restrict__ A, const float* __restrict__ B,
        float* __restrict__ C, int M, int K, int Nd) {
    constexpr int BM = 64, BK = 16;
    constexpr int BN = 32 * TN;
    __shared__ float As[BM * BK];
    __shared__ float Bs[BK * BN];
    int tid = threadIdx.x;
    int m0 = blockIdx.x * BM;
    int n0 = blockIdx.y * BN;
    int tc = tid & 31;
    int tr = tid >> 5;
    float acc[8][TN];
#pragma unroll
    for (int i = 0; i < 8; i++)
#pragma unroll
        for (int j = 0; j < TN; j++) acc[i][j] = 0.f;

    for (int kk = 0; kk < K; kk += BK) {
#pragma unroll
        for (int l = 0; l < (BM * BK) / 256; l++) {
            int e = tid + 256 * l;
            int r = e >> 4, k = e & 15;
            float v = 0.f;
            if (m0 + r < M && kk + k < K) v = A[(size_t)(m0 + r) * K + kk + k];
            As[e] = v;
        }
#pragma unroll
        for (int l = 0; l < (BK * BN) / 256; l++) {
            int e = tid + 256 * l;
            int r = e / BN, c = e % BN;
            float v = 0.f;
            if (kk + r < K) v = B[(size_t)(kk + r) * Nd + n0 + c];
            Bs[e] = v;
        }
        __syncthreads();
#pragma unroll
        for (int k = 0; k < BK; k++) {
            float bv[TN];
#pragma unroll
            for (int j = 0; j < TN; j++) bv[j] = Bs[k * BN + tc * TN + j];
#pragma unroll
            for (int i = 0; i < 8; i++) {
                float a = As[(tr * 8 + i) * BK + k];
#pragma unroll
                for (int j = 0; j < TN; j++) acc[i][j] += a * bv[j];
            }
        }
        __syncthreads();
    }
#pragma unroll
    for (int i = 0; i < 8; i++) {
        int r = m0 + tr * 8 + i;
        if (r < M) {
#pragma unroll
            for (int j = 0; j < TN; j++)
                C[(size_t)r * Nd + n0 + tc * TN + j] = acc[i][j];
        }
    }
}

// ---------------- per-(node,head) attention dots ----------------

template <int H, int C>
__global__ void attn_dots_kernel(const float* __restrict__ hin,
                                 const float* __restrict__ as_, const float* __restrict__ ad_,
                                 float* __restrict__ es, float* __restrict__ ed) {
    int t = blockIdx.x * blockDim.x + threadIdx.x;
    if (t >= N_NODES * H) return;
    int n = t / H, hh = t % H;
    const float* row = hin + (size_t)n * (H * C) + hh * C;
    float s1 = 0.f, s2 = 0.f;
    for (int c = 0; c < C; c++) {
        float v = row[c];
        s1 += v * as_[hh * C + c];
        s2 += v * ad_[hh * C + c];
    }
    es[t] = s1;
    ed[t] = s2;
}

// ---------------- per-dst online-softmax + aggregate + bias/BN/ELU ----------------
// block: max(H*C, 64) threads; one node per block; chunked over in-edges (64/chunk);
// one LPH-lane group per head does the softmax bookkeeping.

template <int H, int C>
__global__ void gat_agg_kernel(const float* __restrict__ hin,
                               const int* __restrict__ rp, const int* __restrict__ col,
                               const float* __restrict__ es, const float* __restrict__ ed,
                               const float* __restrict__ bias, const float* __restrict__ gg,
                               const float* __restrict__ bb,
                               float* __restrict__ out) {
    constexpr int HC  = H * C;
    constexpr int BLK = (HC < 64) ? 64 : HC;
    constexpr int LPH = (BLK / H > 64) ? 64 : (BLK / H);
    constexpr int CH  = 64;
    __shared__ int   s_src[CH];
    __shared__ float s_w[H * CH];
    __shared__ float s_m[H], s_den[H], s_scale[H], s_ed[H];

    int n = blockIdx.x;
    int tid = threadIdx.x;
    int start = rp[n], end = rp[n + 1];
    if (tid < H) {
        s_m[tid] = -INFINITY;
        s_den[tid] = 0.f;
        s_ed[tid] = ed[(size_t)n * H + tid];
    }
    __syncthreads();

    float acc = 0.f;
    int ghh = tid / LPH;
    int glane = tid % LPH;

    for (int cs = start; cs < end; cs += CH) {
        int cnt = min(CH, end - cs);
        if (tid < cnt) s_src[tid] = col[cs + tid];
        __syncthreads();

        // logits, chunk max, online rescale of denominator
        {
            float lmax = -INFINITY;
            for (int e = glane; e < cnt; e += LPH) {
                float l = es[(size_t)s_src[e] * H + ghh] + s_ed[ghh];
                l = (l > 0.f) ? l : 0.2f * l;           // LeakyReLU(0.2)
                s_w[ghh * CH + e] = l;
                lmax = fmaxf(lmax, l);
            }
#pragma unroll
            for (int off = LPH >> 1; off > 0; off >>= 1)
                lmax = fmaxf(lmax, __shfl_xor(lmax, off));
            float mold = s_m[ghh];
            float nm = fmaxf(mold, lmax);
            float fac = expf(mold - nm);                 // 0 on first chunk
            float psum = 0.f;
            for (int e = glane; e < cnt; e += LPH) {
                float w = expf(s_w[ghh * CH + e] - nm);
                s_w[ghh * CH + e] = w;
                psum += w;
            }
#pragma unroll
            for (int off = LPH >> 1; off > 0; off >>= 1)
                psum += __shfl_xor(psum, off);
            if (glane == 0) {
                s_den[ghh] = s_den[ghh] * fac + psum;
                s_m[ghh] = nm;
                s_scale[ghh] = fac;
            }
        }
        __syncthreads();

        // gather-aggregate (channel per thread)
        if (tid < HC) {
            int hh = tid / C;
            float accl = acc * s_scale[hh];
            for (int e = 0; e < cnt; e++) {
                accl += s_w[hh * CH + e] * hin[(size_t)s_src[e] * HC + tid];
            }
            acc = accl;
        }
        __syncthreads();
    }

    if (tid < HC) {
        int hh = tid / C;
        float res = acc / s_den[hh];
        res += bias[tid];                                // + b
        res = res * (gg[tid] / sqrtf(1.0f + 1e-5f)) + bb[tid];   // BN (eval)
        res = (res > 0.f) ? res : expm1f(res);           // ELU
        out[(size_t)n * HC + tid] = res;
    }
}

// ---------------- final linear head [N,32] @ [32,1] + bh ----------------

__global__ void head_kernel(const float* __restrict__ h3, const float* __restrict__ Wh,
                            const float* __restrict__ bh, float* __restrict__ out) {
    int n = blockIdx.x * blockDim.x + threadIdx.x;
    if (n < N_NODES) {
        float s = bh[0];
        const float* row = h3 + (size_t)n * 32;
#pragma unroll
        for (int c = 0; c < 32; c++) s += row[c] * Wh[c];
        out[n] = s;
    }
}

// ---------------- launch ----------------

extern "C" void kernel_launch(void* const* d_in, const int* in_sizes, int n_in,
                              void* d_out, int out_size, void* d_ws, size_t ws_size,
                              hipStream_t stream) {
    const float* x   = (const float*)d_in[0];
    const int*   ei  = (const int*)d_in[1];
    const float* W1  = (const float*)d_in[2];
    const float* a1s = (const float*)d_in[3];
    const float* a1d = (const float*)d_in[4];
    const float* b1  = (const float*)d_in[5];
    const float* W2  = (const float*)d_in[6];
    const float* a2s = (const float*)d_in[7];
    const float* a2d = (const float*)d_in[8];
    const float* b2  = (const float*)d_in[9];
    const float* W3  = (const float*)d_in[10];
    const float* a3s = (const float*)d_in[11];
    const float* a3d = (const float*)d_in[12];
    const float* b3  = (const float*)d_in[13];
    const float* g1  = (const float*)d_in[14];
    const float* be1 = (const float*)d_in[15];
    const float* g2  = (const float*)d_in[16];
    const float* be2 = (const float*)d_in[17];
    const float* g3  = (const float*)d_in[18];
    const float* be3 = (const float*)d_in[19];
    const float* Wh  = (const float*)d_in[20];
    const float* bh  = (const float*)d_in[21];
    float* out = (float*)d_out;

    char* ws = (char*)d_ws;
    size_t off = 0;
    auto alloc = [&](size_t bytes) -> void* {
        void* p = ws + off;
        off += (bytes + 255) & ~(size_t)255;
        return p;
    };
    int*   row_ptr = (int*)alloc((N_NODES + 1) * sizeof(int));
    int*   cursor  = (int*)alloc((N_NODES + 1) * sizeof(int));
    int*   bsum    = (int*)alloc(256 * sizeof(int));
    int*   col_src = (int*)alloc((size_t)ET * sizeof(int));
    float* es      = (float*)alloc((size_t)N_NODES * 8 * sizeof(float));
    float* ed      = (float*)alloc((size_t)N_NODES * 8 * sizeof(float));
    float* bufA    = (float*)alloc((size_t)N_NODES * 512 * sizeof(float));
    float* bufB    = (float*)alloc((size_t)N_NODES * 512 * sizeof(float));

    // ---- CSR build (dst-sorted), shared by all three layers ----
    zero_int_kernel<<<(N_NODES + 1 + 255) / 256, 256, 0, stream>>>(cursor, N_NODES + 1);
    hist_kernel<<<(ET + 255) / 256, 256, 0, stream>>>(ei, cursor);
    scan1_kernel<<<NBLK_SCAN, 256, 0, stream>>>(cursor, row_ptr, bsum);
    scan2_kernel<<<1, 256, 0, stream>>>(bsum, NBLK_SCAN);
    scan3_kernel<<<NBLK_SCAN, 256, 0, stream>>>(row_ptr, bsum, cursor);
    fill_kernel<<<(ET + 255) / 256, 256, 0, stream>>>(ei, cursor, col_src);

    // ---- layer 1: GAT(9 -> 8x64, concat) + BN + ELU ----
    gemm_kernel<4><<<dim3((N_NODES + 63) / 64, 4), 256, 0, stream>>>(x, W1, bufA, N_NODES, 9, 512);
    attn_dots_kernel<8, 64><<<(N_NODES * 8 + 255) / 256, 256, 0, stream>>>(bufA, a1s, a1d, es, ed);
    gat_agg_kernel<8, 64><<<N_NODES, 512, 0, stream>>>(bufA, row_ptr, col_src, es, ed,
                                                       b1, g1, be1, bufB);

    // ---- layer 2: GAT(512 -> 4x32, concat) + BN + ELU ----
    gemm_kernel<4><<<dim3((N_NODES + 63) / 64, 1), 256, 0, stream>>>(bufB, W2, bufA, N_NODES, 512, 128);
    attn_dots_kernel<4, 32><<<(N_NODES * 4 + 255) / 256, 256, 0, stream>>>(bufA, a2s, a2d, es, ed);
    gat_agg_kernel<4, 32><<<N_NODES, 128, 0, stream>>>(bufA, row_ptr, col_src, es, ed,
                                                       b2, g2, be2, bufB);

    // ---- layer 3: GAT(128 -> 1x32, mean) + BN + ELU ----
    gemm_kernel<1><<<dim3((N_NODES + 63) / 64, 1), 256, 0, stream>>>(bufB, W3, bufA, N_NODES, 128, 32);
    attn_dots_kernel<1, 32><<<(N_NODES + 255) / 256, 256, 0, stream>>>(bufA, a3s, a3d, es, ed);
    gat_agg_kernel<1, 32><<<N_NODES, 64, 0, stream>>>(bufA, row_ptr, col_src, es, ed,
                                                      b3, g3, be3, bufB);

    // ---- head ----
    head_kernel<<<(N_NODES + 255) / 256, 256, 0, stream>>>(bufB, Wh, bh, out);
}

// Round 3
// 576.870 us; speedup vs baseline: 1.6409x; 1.6409x over previous
//
#include <hip/hip_runtime.h>
#include <math.h>

#define N_NODES 50000
#define E_EDGES 800000
#define ET (E_EDGES + N_NODES)   // edges + self loops = 850000
#define NBLK_SCAN ((N_NODES + 255) / 256)   // 196

// ---------------- CSR build ----------------

__global__ void zero_int_kernel(int* __restrict__ p, int n) {
    int i = blockIdx.x * blockDim.x + threadIdx.x;
    if (i < n) p[i] = 0;
}

__global__ void hist_kernel(const int* __restrict__ ei, int* __restrict__ cnt) {
    int e = blockIdx.x * blockDim.x + threadIdx.x;
    if (e < ET) {
        int d = (e < E_EDGES) ? ei[E_EDGES + e] : (e - E_EDGES);
        atomicAdd(&cnt[d], 1);
    }
}

__global__ void scan1_kernel(const int* __restrict__ cnt, int* __restrict__ rp,
                             int* __restrict__ bsum) {
    __shared__ int s[256];
    int i = blockIdx.x * 256 + threadIdx.x;
    int v = (i < N_NODES) ? cnt[i] : 0;
    s[threadIdx.x] = v;
    __syncthreads();
    for (int off = 1; off < 256; off <<= 1) {
        int t = (threadIdx.x >= off) ? s[threadIdx.x - off] : 0;
        __syncthreads();
        s[threadIdx.x] += t;
        __syncthreads();
    }
    if (i < N_NODES) rp[i + 1] = s[threadIdx.x];
    if (threadIdx.x == 255) bsum[blockIdx.x] = s[255];
}

__global__ void scan2_kernel(int* __restrict__ bsum, int nb) {
    __shared__ int s[256];
    int v = (threadIdx.x < nb) ? bsum[threadIdx.x] : 0;
    s[threadIdx.x] = v;
    __syncthreads();
    for (int off = 1; off < 256; off <<= 1) {
        int t = (threadIdx.x >= off) ? s[threadIdx.x - off] : 0;
        __syncthreads();
        s[threadIdx.x] += t;
        __syncthreads();
    }
    if (threadIdx.x < nb) bsum[threadIdx.x] = (threadIdx.x == 0) ? 0 : s[threadIdx.x - 1];
}

__global__ void scan3_kernel(int* __restrict__ rp, const int* __restrict__ bsum,
                             int* __restrict__ cursor) {
    int i = blockIdx.x * 256 + threadIdx.x;
    if (i == 0) rp[0] = 0;
    if (i < N_NODES) {
        int incl = rp[i + 1] + bsum[i >> 8];
        rp[i + 1] = incl;
        cursor[i] = incl - cursor[i];
    }
}

__global__ void fill_kernel(const int* __restrict__ ei, int* __restrict__ cursor,
                            int* __restrict__ col) {
    int e = blockIdx.x * blockDim.x + threadIdx.x;
    if (e < ET) {
        int s_, d;
        if (e < E_EDGES) { s_ = ei[e]; d = ei[E_EDGES + e]; }
        else             { s_ = e - E_EDGES; d = s_; }
        int p = atomicAdd(&cursor[d], 1);
        col[p] = s_;
    }
}

// ---------------- layer-1 specialized path (aggregate in x-space, K=9) ----------------

// M[0:72]  = Ms[k][h] = sum_c W1[k, h*64+c]*a1s[h,c]
// M[72:144]= Md[k][h] likewise with a1d
__global__ void prep_attn1_kernel(const float* __restrict__ W1,
                                  const float* __restrict__ a1s,
                                  const float* __restrict__ a1d,
                                  float* __restrict__ M) {
    int t = threadIdx.x;
    if (t < 144) {
        int which = t / 72, idx = t % 72, k = idx / 8, h = idx % 8;
        const float* a = which ? a1d : a1s;
        float s = 0.f;
        for (int c = 0; c < 64; c++) s += W1[k * 512 + h * 64 + c] * a[h * 64 + c];
        M[t] = s;
    }
}

__global__ void es_ed1_kernel(const float* __restrict__ x, const float* __restrict__ M,
                              float* __restrict__ es, float* __restrict__ ed) {
    int n = blockIdx.x * blockDim.x + threadIdx.x;
    if (n >= N_NODES) return;
    float xr[9];
#pragma unroll
    for (int k = 0; k < 9; k++) xr[k] = x[(size_t)n * 9 + k];
#pragma unroll
    for (int h = 0; h < 8; h++) {
        float s1 = 0.f, s2 = 0.f;
#pragma unroll
        for (int k = 0; k < 9; k++) {
            s1 += xr[k] * M[k * 8 + h];
            s2 += xr[k] * M[72 + k * 8 + h];
        }
        es[(size_t)n * 8 + h] = s1;
        ed[(size_t)n * 8 + h] = s2;
    }
}

// per-dst: online softmax over in-edges + aggregate x rows (9 floats) per head.
// aggx[n, h*9 + k] = sum_e alpha[e,h] * x[src_e, k]
__global__ __launch_bounds__(128) void agg1_kernel(const float* __restrict__ x,
        const int* __restrict__ rp, const int* __restrict__ col,
        const float* __restrict__ es, const float* __restrict__ ed,
        float* __restrict__ aggx) {
    __shared__ int   s_src[64];
    __shared__ float s_x[64][9];
    __shared__ float s_es[64][8];
    __shared__ float s_w[8][64];
    __shared__ float s_m[8], s_den[8], s_scale[8], s_ed[8];
    int n = blockIdx.x, tid = threadIdx.x;
    int start = rp[n], end = rp[n + 1];
    if (tid < 8) { s_m[tid] = -INFINITY; s_den[tid] = 0.f; s_ed[tid] = ed[(size_t)n * 8 + tid]; }
    __syncthreads();
    float acc = 0.f;
    int ghh = tid >> 4, glane = tid & 15;
    for (int cs = start; cs < end; cs += 64) {
        int cnt = min(64, end - cs);
        if (tid < cnt) s_src[tid] = col[cs + tid];
        __syncthreads();
        for (int q = tid; q < cnt * 9; q += 128) {
            int e = q / 9, k = q - e * 9;
            s_x[e][k] = x[(size_t)s_src[e] * 9 + k];
        }
        for (int q = tid; q < cnt * 8; q += 128) {
            int e = q >> 3, h = q & 7;
            s_es[e][h] = es[(size_t)s_src[e] * 8 + h];
        }
        __syncthreads();
        float lmax = -INFINITY;
        for (int e = glane; e < cnt; e += 16) {
            float l = s_es[e][ghh] + s_ed[ghh];
            l = (l > 0.f) ? l : 0.2f * l;
            s_w[ghh][e] = l;
            lmax = fmaxf(lmax, l);
        }
#pragma unroll
        for (int off = 8; off > 0; off >>= 1) lmax = fmaxf(lmax, __shfl_xor(lmax, off));
        float mold = s_m[ghh];
        float nm = fmaxf(mold, lmax);
        float fac = __expf(mold - nm);
        float psum = 0.f;
        for (int e = glane; e < cnt; e += 16) {
            float w = __expf(s_w[ghh][e] - nm);
            s_w[ghh][e] = w;
            psum += w;
        }
#pragma unroll
        for (int off = 8; off > 0; off >>= 1) psum += __shfl_xor(psum, off);
        if (glane == 0) { s_den[ghh] = s_den[ghh] * fac + psum; s_m[ghh] = nm; s_scale[ghh] = fac; }
        __syncthreads();
        if (tid < 72) {
            int hh = tid / 9, k = tid - hh * 9;
            float a = acc * s_scale[hh];
            for (int e = 0; e < cnt; e++) a += s_w[hh][e] * s_x[e][k];
            acc = a;
        }
        __syncthreads();
    }
    if (tid < 72) {
        int hh = tid / 9;
        aggx[(size_t)n * 72 + tid] = acc / s_den[hh];
    }
}

// out[n, h*64+c] = ELU(BN( sum_k aggx[n,h*9+k]*W1[k, h*64+c] + b1 ))
__global__ __launch_bounds__(512) void transform1_kernel(const float* __restrict__ aggx,
        const float* __restrict__ W1, const float* __restrict__ b1,
        const float* __restrict__ g1, const float* __restrict__ be1,
        float* __restrict__ out) {
    __shared__ float Ws[9 * 512];
    __shared__ float s_a[72];
    int tid = threadIdx.x;
    for (int q = tid; q < 9 * 512; q += 512) Ws[q] = W1[q];
    int hh = tid >> 6;
    float bias_ = b1[tid];
    float gs = g1[tid] / sqrtf(1.00001f);
    float bb_ = be1[tid];
    __syncthreads();
    for (int n = blockIdx.x; n < N_NODES; n += gridDim.x) {
        if (tid < 72) s_a[tid] = aggx[(size_t)n * 72 + tid];
        __syncthreads();
        float v = bias_;
#pragma unroll
        for (int k = 0; k < 9; k++) v += s_a[hh * 9 + k] * Ws[k * 512 + tid];
        v = v * gs + bb_;
        v = (v > 0.f) ? v : expm1f(v);
        out[(size_t)n * 512 + tid] = v;
        __syncthreads();
    }
}

// ---------------- dense GEMM: C[M,128] = A[M,K] @ B[K,128], K%16==0 ----------------
// BM=128, BN=128, BK=16, 256 threads, 8x8 per thread, float4 loads.

__global__ __launch_bounds__(256) void gemm128_kernel(const float* __restrict__ A,
        const float* __restrict__ B, float* __restrict__ C, int M, int K) {
    constexpr int BM = 128, BK = 16;
    __shared__ float As[BK][BM + 4];
    __shared__ float Bs[BK][128];
    int tid = threadIdx.x;
    int tx = tid & 15, ty = tid >> 4;
    int m0 = blockIdx.x * BM;
    float acc[8][8];
#pragma unroll
    for (int i = 0; i < 8; i++)
#pragma unroll
        for (int j = 0; j < 8; j++) acc[i][j] = 0.f;

    for (int kk = 0; kk < K; kk += BK) {
#pragma unroll
        for (int i = 0; i < 2; i++) {
            int q = tid * 2 + i;
            int r = q >> 2, seg = q & 3;
            float4 v = make_float4(0.f, 0.f, 0.f, 0.f);
            if (m0 + r < M) v = *(const float4*)&A[(size_t)(m0 + r) * K + kk + seg * 4];
            As[seg * 4 + 0][r] = v.x;
            As[seg * 4 + 1][r] = v.y;
            As[seg * 4 + 2][r] = v.z;
            As[seg * 4 + 3][r] = v.w;
        }
#pragma unroll
        for (int i = 0; i < 2; i++) {
            int q = tid * 2 + i;
            int r = q >> 5, c4 = q & 31;
            *(float4*)&Bs[r][c4 * 4] = *(const float4*)&B[(size_t)(kk + r) * 128 + c4 * 4];
        }
        __syncthreads();
#pragma unroll
        for (int k = 0; k < BK; k++) {
            float a[8], b[8];
#pragma unroll
            for (int i = 0; i < 8; i++) a[i] = As[k][i * 16 + ty];
#pragma unroll
            for (int j = 0; j < 8; j++) b[j] = Bs[k][j * 16 + tx];
#pragma unroll
            for (int i = 0; i < 8; i++)
#pragma unroll
                for (int j = 0; j < 8; j++) acc[i][j] += a[i] * b[j];
        }
        __syncthreads();
    }
#pragma unroll
    for (int i = 0; i < 8; i++) {
        int r = m0 + i * 16 + ty;
        if (r < M) {
#pragma unroll
            for (int j = 0; j < 8; j++)
                C[(size_t)r * 128 + j * 16 + tx] = acc[i][j];
        }
    }
}

// ---------------- small GEMM (layer 3): C[M,Nd] = A[M,K]@B[K,Nd] ----------------

template <int TN>
__global__ __launch_bounds__(256) void gemm_kernel(
        const float* __restrict__ A, const float* __restrict__ B,
        float* __restrict__ C, int M, int K, int Nd) {
    constexpr int BM = 64, BK = 16;
    constexpr int BN = 32 * TN;
    __shared__ float As[BM * BK];
    __shared__ float Bs[BK * BN];
    int tid = threadIdx.x;
    int m0 = blockIdx.x * BM;
    int n0 = blockIdx.y * BN;
    int tc = tid & 31;
    int tr = tid >> 5;
    float acc[8][TN];
#pragma unroll
    for (int i = 0; i < 8; i++)
#pragma unroll
        for (int j = 0; j < TN; j++) acc[i][j] = 0.f;

    for (int kk = 0; kk < K; kk += BK) {
#pragma unroll
        for (int l = 0; l < (BM * BK) / 256; l++) {
            int e = tid + 256 * l;
            int r = e >> 4, k = e & 15;
            float v = 0.f;
            if (m0 + r < M && kk + k < K) v = A[(size_t)(m0 + r) * K + kk + k];
            As[e] = v;
        }
#pragma unroll
        for (int l = 0; l < (BK * BN) / 256; l++) {
            int e = tid + 256 * l;
            int r = e / BN, c = e % BN;
            float v = 0.f;
            if (kk + r < K) v = B[(size_t)(kk + r) * Nd + n0 + c];
            Bs[e] = v;
        }
        __syncthreads();
#pragma unroll
        for (int k = 0; k < BK; k++) {
            float bv[TN];
#pragma unroll
            for (int j = 0; j < TN; j++) bv[j] = Bs[k * BN + tc * TN + j];
#pragma unroll
            for (int i = 0; i < 8; i++) {
                float a = As[(tr * 8 + i) * BK + k];
#pragma unroll
                for (int j = 0; j < TN; j++) acc[i][j] += a * bv[j];
            }
        }
        __syncthreads();
    }
#pragma unroll
    for (int i = 0; i < 8; i++) {
        int r = m0 + tr * 8 + i;
        if (r < M) {
#pragma unroll
            for (int j = 0; j < TN; j++)
                C[(size_t)r * Nd + n0 + tc * TN + j] = acc[i][j];
        }
    }
}

// ---------------- per-(node,head) attention dots ----------------

template <int H, int C>
__global__ void attn_dots_kernel(const float* __restrict__ hin,
                                 const float* __restrict__ as_, const float* __restrict__ ad_,
                                 float* __restrict__ es, float* __restrict__ ed) {
    int t = blockIdx.x * blockDim.x + threadIdx.x;
    if (t >= N_NODES * H) return;
    int n = t / H, hh = t % H;
    const float* row = hin + (size_t)n * (H * C) + hh * C;
    float s1 = 0.f, s2 = 0.f;
    for (int c = 0; c < C; c++) {
        float v = row[c];
        s1 += v * as_[hh * C + c];
        s2 += v * ad_[hh * C + c];
    }
    es[t] = s1;
    ed[t] = s2;
}

// ---------------- per-dst online-softmax + aggregate + bias/BN/ELU ----------------

template <int H, int C>
__global__ void gat_agg_kernel(const float* __restrict__ hin,
                               const int* __restrict__ rp, const int* __restrict__ col,
                               const float* __restrict__ es, const float* __restrict__ ed,
                               const float* __restrict__ bias, const float* __restrict__ gg,
                               const float* __restrict__ bb,
                               float* __restrict__ out) {
    constexpr int HC  = H * C;
    constexpr int BLK = (HC < 64) ? 64 : HC;
    constexpr int LPH = (BLK / H > 64) ? 64 : (BLK / H);
    constexpr int CH  = 64;
    __shared__ int   s_src[CH];
    __shared__ float s_w[H * CH];
    __shared__ float s_m[H], s_den[H], s_scale[H], s_ed[H];

    int n = blockIdx.x;
    int tid = threadIdx.x;
    int start = rp[n], end = rp[n + 1];
    if (tid < H) {
        s_m[tid] = -INFINITY;
        s_den[tid] = 0.f;
        s_ed[tid] = ed[(size_t)n * H + tid];
    }
    __syncthreads();

    float acc = 0.f;
    int ghh = tid / LPH;
    int glane = tid % LPH;

    for (int cs = start; cs < end; cs += CH) {
        int cnt = min(CH, end - cs);
        if (tid < cnt) s_src[tid] = col[cs + tid];
        __syncthreads();

        {
            float lmax = -INFINITY;
            for (int e = glane; e < cnt; e += LPH) {
                float l = es[(size_t)s_src[e] * H + ghh] + s_ed[ghh];
                l = (l > 0.f) ? l : 0.2f * l;
                s_w[ghh * CH + e] = l;
                lmax = fmaxf(lmax, l);
            }
#pragma unroll
            for (int off = LPH >> 1; off > 0; off >>= 1)
                lmax = fmaxf(lmax, __shfl_xor(lmax, off));
            float mold = s_m[ghh];
            float nm = fmaxf(mold, lmax);
            float fac = __expf(mold - nm);
            float psum = 0.f;
            for (int e = glane; e < cnt; e += LPH) {
                float w = __expf(s_w[ghh * CH + e] - nm);
                s_w[ghh * CH + e] = w;
                psum += w;
            }
#pragma unroll
            for (int off = LPH >> 1; off > 0; off >>= 1)
                psum += __shfl_xor(psum, off);
            if (glane == 0) {
                s_den[ghh] = s_den[ghh] * fac + psum;
                s_m[ghh] = nm;
                s_scale[ghh] = fac;
            }
        }
        __syncthreads();

        if (tid < HC) {
            int hh = tid / C;
            float a0 = acc * s_scale[hh], a1 = 0.f, a2 = 0.f, a3 = 0.f;
            int e = 0;
            for (; e + 4 <= cnt; e += 4) {
                a0 += s_w[hh * CH + e]     * hin[(size_t)s_src[e] * HC + tid];
                a1 += s_w[hh * CH + e + 1] * hin[(size_t)s_src[e + 1] * HC + tid];
                a2 += s_w[hh * CH + e + 2] * hin[(size_t)s_src[e + 2] * HC + tid];
                a3 += s_w[hh * CH + e + 3] * hin[(size_t)s_src[e + 3] * HC + tid];
            }
            for (; e < cnt; e++) a0 += s_w[hh * CH + e] * hin[(size_t)s_src[e] * HC + tid];
            acc = a0 + a1 + a2 + a3;
        }
        __syncthreads();
    }

    if (tid < HC) {
        int hh = tid / C;
        float res = acc / s_den[hh];
        res += bias[tid];
        res = res * (gg[tid] / sqrtf(1.00001f)) + bb[tid];
        res = (res > 0.f) ? res : expm1f(res);
        out[(size_t)n * HC + tid] = res;
    }
}

// ---------------- final linear head [N,32] @ [32,1] + bh ----------------

__global__ void head_kernel(const float* __restrict__ h3, const float* __restrict__ Wh,
                            const float* __restrict__ bh, float* __restrict__ out) {
    int n = blockIdx.x * blockDim.x + threadIdx.x;
    if (n < N_NODES) {
        float s = bh[0];
        const float* row = h3 + (size_t)n * 32;
#pragma unroll
        for (int c = 0; c < 32; c++) s += row[c] * Wh[c];
        out[n] = s;
    }
}

// ---------------- launch ----------------

extern "C" void kernel_launch(void* const* d_in, const int* in_sizes, int n_in,
                              void* d_out, int out_size, void* d_ws, size_t ws_size,
                              hipStream_t stream) {
    const float* x   = (const float*)d_in[0];
    const int*   ei  = (const int*)d_in[1];
    const float* W1  = (const float*)d_in[2];
    const float* a1s = (const float*)d_in[3];
    const float* a1d = (const float*)d_in[4];
    const float* b1  = (const float*)d_in[5];
    const float* W2  = (const float*)d_in[6];
    const float* a2s = (const float*)d_in[7];
    const float* a2d = (const float*)d_in[8];
    const float* b2  = (const float*)d_in[9];
    const float* W3  = (const float*)d_in[10];
    const float* a3s = (const float*)d_in[11];
    const float* a3d = (const float*)d_in[12];
    const float* b3  = (const float*)d_in[13];
    const float* g1  = (const float*)d_in[14];
    const float* be1 = (const float*)d_in[15];
    const float* g2  = (const float*)d_in[16];
    const float* be2 = (const float*)d_in[17];
    const float* g3  = (const float*)d_in[18];
    const float* be3 = (const float*)d_in[19];
    const float* Wh  = (const float*)d_in[20];
    const float* bh  = (const float*)d_in[21];
    float* out = (float*)d_out;

    char* ws = (char*)d_ws;
    size_t off = 0;
    auto alloc = [&](size_t bytes) -> void* {
        void* p = ws + off;
        off += (bytes + 255) & ~(size_t)255;
        return p;
    };
    int*   row_ptr = (int*)alloc((N_NODES + 1) * sizeof(int));
    int*   cursor  = (int*)alloc((N_NODES + 1) * sizeof(int));
    int*   bsum    = (int*)alloc(256 * sizeof(int));
    int*   col_src = (int*)alloc((size_t)ET * sizeof(int));
    float* es      = (float*)alloc((size_t)N_NODES * 8 * sizeof(float));
    float* ed      = (float*)alloc((size_t)N_NODES * 8 * sizeof(float));
    float* bufA    = (float*)alloc((size_t)N_NODES * 512 * sizeof(float));
    float* bufB    = (float*)alloc((size_t)N_NODES * 512 * sizeof(float));
    // tiny Ms/Md buffer carved from the tail of d_ws (aggx reuses bufA)
    float* M1 = (float*)(ws + ((ws_size - 1024) & ~(size_t)255));
    float* aggx = bufA;   // [N, 72] — bufA is dead until gemm2 output

    // ---- CSR build (dst-sorted), shared by all three layers ----
    zero_int_kernel<<<(N_NODES + 1 + 255) / 256, 256, 0, stream>>>(cursor, N_NODES + 1);
    hist_kernel<<<(ET + 255) / 256, 256, 0, stream>>>(ei, cursor);
    scan1_kernel<<<NBLK_SCAN, 256, 0, stream>>>(cursor, row_ptr, bsum);
    scan2_kernel<<<1, 256, 0, stream>>>(bsum, NBLK_SCAN);
    scan3_kernel<<<NBLK_SCAN, 256, 0, stream>>>(row_ptr, bsum, cursor);
    fill_kernel<<<(ET + 255) / 256, 256, 0, stream>>>(ei, cursor, col_src);

    // ---- layer 1: GAT(9 -> 8x64, concat) + BN + ELU, aggregated in x-space ----
    prep_attn1_kernel<<<1, 256, 0, stream>>>(W1, a1s, a1d, M1);
    es_ed1_kernel<<<(N_NODES + 255) / 256, 256, 0, stream>>>(x, M1, es, ed);
    agg1_kernel<<<N_NODES, 128, 0, stream>>>(x, row_ptr, col_src, es, ed, aggx);
    transform1_kernel<<<1024, 512, 0, stream>>>(aggx, W1, b1, g1, be1, bufB);

    // ---- layer 2: GAT(512 -> 4x32, concat) + BN + ELU ----
    gemm128_kernel<<<(N_NODES + 127) / 128, 256, 0, stream>>>(bufB, W2, bufA, N_NODES, 512);
    attn_dots_kernel<4, 32><<<(N_NODES * 4 + 255) / 256, 256, 0, stream>>>(bufA, a2s, a2d, es, ed);
    gat_agg_kernel<4, 32><<<N_NODES, 128, 0, stream>>>(bufA, row_ptr, col_src, es, ed,
                                                       b2, g2, be2, bufB);

    // ---- layer 3: GAT(128 -> 1x32, mean) + BN + ELU ----
    gemm_kernel<1><<<dim3((N_NODES + 63) / 64, 1), 256, 0, stream>>>(bufB, W3, bufA, N_NODES, 128, 32);
    attn_dots_kernel<1, 32><<<(N_NODES + 255) / 256, 256, 0, stream>>>(bufA, a3s, a3d, es, ed);
    gat_agg_kernel<1, 32><<<N_NODES, 64, 0, stream>>>(bufA, row_ptr, col_src, es, ed,
                                                      b3, g3, be3, bufB);

    // ---- head ----
    head_kernel<<<(N_NODES + 255) / 256, 256, 0, stream>>>(bufB, Wh, bh, out);
}

// Round 4
// 478.276 us; speedup vs baseline: 1.9792x; 1.2061x over previous
//
#include <hip/hip_runtime.h>
#include <hip/hip_bf16.h>
#include <math.h>

#define N_NODES 50000
#define E_EDGES 800000
#define ET (E_EDGES + N_NODES)   // edges + self loops = 850000
#define NBLK_SCAN ((N_NODES + 255) / 256)   // 196
#define MPAD 50048               // 391 * 128

typedef __attribute__((ext_vector_type(8))) short bf16x8;
typedef __attribute__((ext_vector_type(4))) float f32x4;

// ---------------- CSR build ----------------

__global__ void zero_int_kernel(int* __restrict__ p, int n) {
    int i = blockIdx.x * blockDim.x + threadIdx.x;
    if (i < n) p[i] = 0;
}

__global__ void hist_kernel(const int* __restrict__ ei, int* __restrict__ cnt) {
    int e = blockIdx.x * blockDim.x + threadIdx.x;
    if (e < ET) {
        int d = (e < E_EDGES) ? ei[E_EDGES + e] : (e - E_EDGES);
        atomicAdd(&cnt[d], 1);
    }
}

__global__ void scan1_kernel(const int* __restrict__ cnt, int* __restrict__ rp,
                             int* __restrict__ bsum) {
    __shared__ int s[256];
    int i = blockIdx.x * 256 + threadIdx.x;
    int v = (i < N_NODES) ? cnt[i] : 0;
    s[threadIdx.x] = v;
    __syncthreads();
    for (int off = 1; off < 256; off <<= 1) {
        int t = (threadIdx.x >= off) ? s[threadIdx.x - off] : 0;
        __syncthreads();
        s[threadIdx.x] += t;
        __syncthreads();
    }
    if (i < N_NODES) rp[i + 1] = s[threadIdx.x];
    if (threadIdx.x == 255) bsum[blockIdx.x] = s[255];
}

__global__ void scan2_kernel(int* __restrict__ bsum, int nb) {
    __shared__ int s[256];
    int v = (threadIdx.x < nb) ? bsum[threadIdx.x] : 0;
    s[threadIdx.x] = v;
    __syncthreads();
    for (int off = 1; off < 256; off <<= 1) {
        int t = (threadIdx.x >= off) ? s[threadIdx.x - off] : 0;
        __syncthreads();
        s[threadIdx.x] += t;
        __syncthreads();
    }
    if (threadIdx.x < nb) bsum[threadIdx.x] = (threadIdx.x == 0) ? 0 : s[threadIdx.x - 1];
}

__global__ void scan3_kernel(int* __restrict__ rp, const int* __restrict__ bsum,
                             int* __restrict__ cursor) {
    int i = blockIdx.x * 256 + threadIdx.x;
    if (i == 0) rp[0] = 0;
    if (i < N_NODES) {
        int incl = rp[i + 1] + bsum[i >> 8];
        rp[i + 1] = incl;
        cursor[i] = incl - cursor[i];
    }
}

__global__ void fill_kernel(const int* __restrict__ ei, int* __restrict__ cursor,
                            int* __restrict__ col) {
    int e = blockIdx.x * blockDim.x + threadIdx.x;
    if (e < ET) {
        int s_, d;
        if (e < E_EDGES) { s_ = ei[e]; d = ei[E_EDGES + e]; }
        else             { s_ = e - E_EDGES; d = s_; }
        int p = atomicAdd(&cursor[d], 1);
        col[p] = s_;
    }
}

// ---------------- layer-1 specialized path (aggregate in x-space, K=9) ----------------

__global__ void prep_attn1_kernel(const float* __restrict__ W1,
                                  const float* __restrict__ a1s,
                                  const float* __restrict__ a1d,
                                  float* __restrict__ M) {
    int t = threadIdx.x;
    if (t < 144) {
        int which = t / 72, idx = t % 72, k = idx / 8, h = idx % 8;
        const float* a = which ? a1d : a1s;
        float s = 0.f;
        for (int c = 0; c < 64; c++) s += W1[k * 512 + h * 64 + c] * a[h * 64 + c];
        M[t] = s;
    }
}

__global__ void es_ed1_kernel(const float* __restrict__ x, const float* __restrict__ M,
                              float* __restrict__ es, float* __restrict__ ed) {
    int n = blockIdx.x * blockDim.x + threadIdx.x;
    if (n >= N_NODES) return;
    float xr[9];
#pragma unroll
    for (int k = 0; k < 9; k++) xr[k] = x[(size_t)n * 9 + k];
#pragma unroll
    for (int h = 0; h < 8; h++) {
        float s1 = 0.f, s2 = 0.f;
#pragma unroll
        for (int k = 0; k < 9; k++) {
            s1 += xr[k] * M[k * 8 + h];
            s2 += xr[k] * M[72 + k * 8 + h];
        }
        es[(size_t)n * 8 + h] = s1;
        ed[(size_t)n * 8 + h] = s2;
    }
}

// per-dst: online softmax over in-edges + aggregate x rows (9 floats) per head.
__global__ __launch_bounds__(128) void agg1_kernel(const float* __restrict__ x,
        const int* __restrict__ rp, const int* __restrict__ col,
        const float* __restrict__ es, const float* __restrict__ ed,
        float* __restrict__ aggx) {
    __shared__ int   s_src[64];
    __shared__ float s_x[64][9];
    __shared__ float s_es[64][8];
    __shared__ float s_w[8][64];
    __shared__ float s_m[8], s_den[8], s_scale[8], s_ed[8];
    int n = blockIdx.x, tid = threadIdx.x;
    int start = rp[n], end = rp[n + 1];
    if (tid < 8) { s_m[tid] = -INFINITY; s_den[tid] = 0.f; s_ed[tid] = ed[(size_t)n * 8 + tid]; }
    __syncthreads();
    float acc = 0.f;
    int ghh = tid >> 4, glane = tid & 15;
    for (int cs = start; cs < end; cs += 64) {
        int cnt = min(64, end - cs);
        if (tid < cnt) s_src[tid] = col[cs + tid];
        __syncthreads();
        for (int q = tid; q < cnt * 9; q += 128) {
            int e = q / 9, k = q - e * 9;
            s_x[e][k] = x[(size_t)s_src[e] * 9 + k];
        }
        for (int q = tid; q < cnt * 8; q += 128) {
            int e = q >> 3, h = q & 7;
            s_es[e][h] = es[(size_t)s_src[e] * 8 + h];
        }
        __syncthreads();
        float lmax = -INFINITY;
        for (int e = glane; e < cnt; e += 16) {
            float l = s_es[e][ghh] + s_ed[ghh];
            l = (l > 0.f) ? l : 0.2f * l;
            s_w[ghh][e] = l;
            lmax = fmaxf(lmax, l);
        }
#pragma unroll
        for (int off = 8; off > 0; off >>= 1) lmax = fmaxf(lmax, __shfl_xor(lmax, off));
        float mold = s_m[ghh];
        float nm = fmaxf(mold, lmax);
        float fac = __expf(mold - nm);
        float psum = 0.f;
        for (int e = glane; e < cnt; e += 16) {
            float w = __expf(s_w[ghh][e] - nm);
            s_w[ghh][e] = w;
            psum += w;
        }
#pragma unroll
        for (int off = 8; off > 0; off >>= 1) psum += __shfl_xor(psum, off);
        if (glane == 0) { s_den[ghh] = s_den[ghh] * fac + psum; s_m[ghh] = nm; s_scale[ghh] = fac; }
        __syncthreads();
        if (tid < 72) {
            int hh = tid / 9, k = tid - hh * 9;
            float a = acc * s_scale[hh];
            for (int e = 0; e < cnt; e++) a += s_w[hh][e] * s_x[e][k];
            acc = a;
        }
        __syncthreads();
    }
    if (tid < 72) {
        int hh = tid / 9;
        aggx[(size_t)n * 72 + tid] = acc / s_den[hh];
    }
}

// out = ELU(BN( aggx@W1 + b1 )) -> written as bf16 hi/lo split [MPAD,512]
__global__ __launch_bounds__(512) void transform1_kernel(const float* __restrict__ aggx,
        const float* __restrict__ W1, const float* __restrict__ b1,
        const float* __restrict__ g1, const float* __restrict__ be1,
        __hip_bfloat16* __restrict__ Ah, __hip_bfloat16* __restrict__ Al) {
    __shared__ float Ws[9 * 512];
    __shared__ float s_a[72];
    int tid = threadIdx.x;
    for (int q = tid; q < 9 * 512; q += 512) Ws[q] = W1[q];
    int hh = tid >> 6;
    float bias_ = b1[tid];
    float gs = g1[tid] / sqrtf(1.00001f);
    float bb_ = be1[tid];
    __syncthreads();
    for (int n = blockIdx.x; n < N_NODES; n += gridDim.x) {
        if (tid < 72) s_a[tid] = aggx[(size_t)n * 72 + tid];
        __syncthreads();
        float v = bias_;
#pragma unroll
        for (int k = 0; k < 9; k++) v += s_a[hh * 9 + k] * Ws[k * 512 + tid];
        v = v * gs + bb_;
        v = (v > 0.f) ? v : expm1f(v);
        __hip_bfloat16 hi = __float2bfloat16(v);
        float r = v - __bfloat162float(hi);
        Ah[(size_t)n * 512 + tid] = hi;
        Al[(size_t)n * 512 + tid] = __float2bfloat16(r);
        __syncthreads();
    }
}

// W2 [512][128] fp32 -> W2^T hi/lo [128][512] bf16
__global__ void prep_w2_kernel(const float* __restrict__ W2,
                               __hip_bfloat16* __restrict__ Wh,
                               __hip_bfloat16* __restrict__ Wl) {
    int t = blockIdx.x * 256 + threadIdx.x;
    if (t < 512 * 128) {
        int k = t >> 7, c = t & 127;
        float v = W2[t];
        __hip_bfloat16 hi = __float2bfloat16(v);
        float r = v - __bfloat162float(hi);
        Wh[c * 512 + k] = hi;
        Wl[c * 512 + k] = __float2bfloat16(r);
    }
}

// ---------------- layer-2 GEMM via MFMA: C[N,128] = A[N,512] @ W2 ----------------
// A given as bf16 hi/lo, W as W^T bf16 hi/lo. 3-term split: AhWh + AlWh + AhWl.
// mfma(X, Y) computes D[i][j] = sum_k X[i][k]*Y[j][k]; both operand frags:
// lane holds row lane&15, k-granule lane>>4 (8 contiguous bf16 = 16B).
// LDS tiles [128 rows][64 k] bf16, 16B-granule XOR swizzle (kg ^= row&7).

__global__ __launch_bounds__(256) void gemm2_mfma_kernel(
        const __hip_bfloat16* __restrict__ Ah, const __hip_bfloat16* __restrict__ Al,
        const __hip_bfloat16* __restrict__ Wh, const __hip_bfloat16* __restrict__ Wl,
        float* __restrict__ C) {
    __shared__ short lds[32768];   // 64 KB: Ah | Al | Wh | Wl, 8192 shorts each
    int tid = threadIdx.x;
    int wv = tid >> 6;
    int lane = tid & 63;
    int lrow = lane & 15, kgrp = lane >> 4;
    int m0 = blockIdx.x * 128;

    f32x4 acc[2][8];
#pragma unroll
    for (int m = 0; m < 2; m++)
#pragma unroll
        for (int n = 0; n < 8; n++) acc[m][n] = (f32x4){0.f, 0.f, 0.f, 0.f};

    for (int kk = 0; kk < 512; kk += 64) {
        // ---- stage 4 tiles (reg-staged, swizzled ds_write_b128) ----
#pragma unroll
        for (int tI = 0; tI < 4; tI++) {
            const __hip_bfloat16* src = (tI == 0) ? Ah : (tI == 1) ? Al : (tI == 2) ? Wh : Wl;
            int rowBase = (tI < 2) ? m0 : 0;
#pragma unroll
            for (int i = 0; i < 4; i++) {
                int gid = tid + 256 * i;
                int row = gid >> 3, kg = gid & 7;
                bf16x8 v = *(const bf16x8*)(src + (size_t)(rowBase + row) * 512 + kk + kg * 8);
                *(bf16x8*)(lds + tI * 8192 + row * 64 + ((kg ^ (row & 7)) << 3)) = v;
            }
        }
        __syncthreads();
        // ---- compute: 2 k-substeps of 32 ----
#pragma unroll
        for (int ks = 0; ks < 2; ks++) {
            bf16x8 ah[2], al[2];
#pragma unroll
            for (int m = 0; m < 2; m++) {
                int row = wv * 32 + m * 16 + lrow;
                int kg = ks * 4 + kgrp;
                int so = row * 64 + ((kg ^ (row & 7)) << 3);
                ah[m] = *(const bf16x8*)(lds + so);
                al[m] = *(const bf16x8*)(lds + 8192 + so);
            }
#pragma unroll
            for (int n = 0; n < 8; n++) {
                int colr = n * 16 + lrow;
                int kg = ks * 4 + kgrp;
                int so = colr * 64 + ((kg ^ (colr & 7)) << 3);
                bf16x8 wh = *(const bf16x8*)(lds + 16384 + so);
                bf16x8 wl = *(const bf16x8*)(lds + 24576 + so);
#pragma unroll
                for (int m = 0; m < 2; m++) {
                    acc[m][n] = __builtin_amdgcn_mfma_f32_16x16x32_bf16(ah[m], wh, acc[m][n], 0, 0, 0);
                    acc[m][n] = __builtin_amdgcn_mfma_f32_16x16x32_bf16(al[m], wh, acc[m][n], 0, 0, 0);
                    acc[m][n] = __builtin_amdgcn_mfma_f32_16x16x32_bf16(ah[m], wl, acc[m][n], 0, 0, 0);
                }
            }
        }
        __syncthreads();
    }
    // ---- store: D col = lane&15 (W^T row = out col), row = (lane>>4)*4 + reg ----
#pragma unroll
    for (int m = 0; m < 2; m++) {
#pragma unroll
        for (int n = 0; n < 8; n++) {
#pragma unroll
            for (int r = 0; r < 4; r++) {
                int row = m0 + wv * 32 + m * 16 + (lane >> 4) * 4 + r;
                int colc = n * 16 + (lane & 15);
                if (row < N_NODES) C[(size_t)row * 128 + colc] = acc[m][n][r];
            }
        }
    }
}

// ---------------- small GEMM (layer 3): C[M,Nd] = A[M,K]@B[K,Nd] ----------------

template <int TN>
__global__ __launch_bounds__(256) void gemm_kernel(
        const float* __restrict__ A, const float* __restrict__ B,
        float* __restrict__ C, int M, int K, int Nd) {
    constexpr int BM = 64, BK = 16;
    constexpr int BN = 32 * TN;
    __shared__ float As[BM * BK];
    __shared__ float Bs[BK * BN];
    int tid = threadIdx.x;
    int m0 = blockIdx.x * BM;
    int n0 = blockIdx.y * BN;
    int tc = tid & 31;
    int tr = tid >> 5;
    float acc[8][TN];
#pragma unroll
    for (int i = 0; i < 8; i++)
#pragma unroll
        for (int j = 0; j < TN; j++) acc[i][j] = 0.f;

    for (int kk = 0; kk < K; kk += BK) {
#pragma unroll
        for (int l = 0; l < (BM * BK) / 256; l++) {
            int e = tid + 256 * l;
            int r = e >> 4, k = e & 15;
            float v = 0.f;
            if (m0 + r < M && kk + k < K) v = A[(size_t)(m0 + r) * K + kk + k];
            As[e] = v;
        }
#pragma unroll
        for (int l = 0; l < (BK * BN) / 256; l++) {
            int e = tid + 256 * l;
            int r = e / BN, c = e % BN;
            float v = 0.f;
            if (kk + r < K) v = B[(size_t)(kk + r) * Nd + n0 + c];
            Bs[e] = v;
        }
        __syncthreads();
#pragma unroll
        for (int k = 0; k < BK; k++) {
            float bv[TN];
#pragma unroll
            for (int j = 0; j < TN; j++) bv[j] = Bs[k * BN + tc * TN + j];
#pragma unroll
            for (int i = 0; i < 8; i++) {
                float a = As[(tr * 8 + i) * BK + k];
#pragma unroll
                for (int j = 0; j < TN; j++) acc[i][j] += a * bv[j];
            }
        }
        __syncthreads();
    }
#pragma unroll
    for (int i = 0; i < 8; i++) {
        int r = m0 + tr * 8 + i;
        if (r < M) {
#pragma unroll
            for (int j = 0; j < TN; j++)
                C[(size_t)r * Nd + n0 + tc * TN + j] = acc[i][j];
        }
    }
}

// ---------------- per-(node,head) attention dots ----------------

template <int H, int C>
__global__ void attn_dots_kernel(const float* __restrict__ hin,
                                 const float* __restrict__ as_, const float* __restrict__ ad_,
                                 float* __restrict__ es, float* __restrict__ ed) {
    int t = blockIdx.x * blockDim.x + threadIdx.x;
    if (t >= N_NODES * H) return;
    int n = t / H, hh = t % H;
    const float* row = hin + (size_t)n * (H * C) + hh * C;
    float s1 = 0.f, s2 = 0.f;
    for (int c = 0; c < C; c++) {
        float v = row[c];
        s1 += v * as_[hh * C + c];
        s2 += v * ad_[hh * C + c];
    }
    es[t] = s1;
    ed[t] = s2;
}

// ---------------- per-dst online-softmax + aggregate + bias/BN/ELU ----------------

template <int H, int C>
__global__ void gat_agg_kernel(const float* __restrict__ hin,
                               const int* __restrict__ rp, const int* __restrict__ col,
                               const float* __restrict__ es, const float* __restrict__ ed,
                               const float* __restrict__ bias, const float* __restrict__ gg,
                               const float* __restrict__ bb,
                               float* __restrict__ out) {
    constexpr int HC  = H * C;
    constexpr int BLK = (HC < 64) ? 64 : HC;
    constexpr int LPH = (BLK / H > 64) ? 64 : (BLK / H);
    constexpr int CH  = 64;
    __shared__ int   s_src[CH];
    __shared__ float s_w[H * CH];
    __shared__ float s_m[H], s_den[H], s_scale[H], s_ed[H];

    int n = blockIdx.x;
    int tid = threadIdx.x;
    int start = rp[n], end = rp[n + 1];
    if (tid < H) {
        s_m[tid] = -INFINITY;
        s_den[tid] = 0.f;
        s_ed[tid] = ed[(size_t)n * H + tid];
    }
    __syncthreads();

    float acc = 0.f;
    int ghh = tid / LPH;
    int glane = tid % LPH;

    for (int cs = start; cs < end; cs += CH) {
        int cnt = min(CH, end - cs);
        if (tid < cnt) s_src[tid] = col[cs + tid];
        __syncthreads();

        {
            float lmax = -INFINITY;
            for (int e = glane; e < cnt; e += LPH) {
                float l = es[(size_t)s_src[e] * H + ghh] + s_ed[ghh];
                l = (l > 0.f) ? l : 0.2f * l;
                s_w[ghh * CH + e] = l;
                lmax = fmaxf(lmax, l);
            }
#pragma unroll
            for (int off = LPH >> 1; off > 0; off >>= 1)
                lmax = fmaxf(lmax, __shfl_xor(lmax, off));
            float mold = s_m[ghh];
            float nm = fmaxf(mold, lmax);
            float fac = __expf(mold - nm);
            float psum = 0.f;
            for (int e = glane; e < cnt; e += LPH) {
                float w = __expf(s_w[ghh * CH + e] - nm);
                s_w[ghh * CH + e] = w;
                psum += w;
            }
#pragma unroll
            for (int off = LPH >> 1; off > 0; off >>= 1)
                psum += __shfl_xor(psum, off);
            if (glane == 0) {
                s_den[ghh] = s_den[ghh] * fac + psum;
                s_m[ghh] = nm;
                s_scale[ghh] = fac;
            }
        }
        __syncthreads();

        if (tid < HC) {
            int hh = tid / C;
            float a0 = acc * s_scale[hh], a1 = 0.f, a2 = 0.f, a3 = 0.f;
            int e = 0;
            for (; e + 4 <= cnt; e += 4) {
                a0 += s_w[hh * CH + e]     * hin[(size_t)s_src[e] * HC + tid];
                a1 += s_w[hh * CH + e + 1] * hin[(size_t)s_src[e + 1] * HC + tid];
                a2 += s_w[hh * CH + e + 2] * hin[(size_t)s_src[e + 2] * HC + tid];
                a3 += s_w[hh * CH + e + 3] * hin[(size_t)s_src[e + 3] * HC + tid];
            }
            for (; e < cnt; e++) a0 += s_w[hh * CH + e] * hin[(size_t)s_src[e] * HC + tid];
            acc = a0 + a1 + a2 + a3;
        }
        __syncthreads();
    }

    if (tid < HC) {
        int hh = tid / C;
        float res = acc / s_den[hh];
        res += bias[tid];
        res = res * (gg[tid] / sqrtf(1.00001f)) + bb[tid];
        res = (res > 0.f) ? res : expm1f(res);
        out[(size_t)n * HC + tid] = res;
    }
}

// ---------------- final linear head [N,32] @ [32,1] + bh ----------------

__global__ void head_kernel(const float* __restrict__ h3, const float* __restrict__ Wh,
                            const float* __restrict__ bh, float* __restrict__ out) {
    int n = blockIdx.x * blockDim.x + threadIdx.x;
    if (n < N_NODES) {
        float s = bh[0];
        const float* row = h3 + (size_t)n * 32;
#pragma unroll
        for (int c = 0; c < 32; c++) s += row[c] * Wh[c];
        out[n] = s;
    }
}

// ---------------- launch ----------------

extern "C" void kernel_launch(void* const* d_in, const int* in_sizes, int n_in,
                              void* d_out, int out_size, void* d_ws, size_t ws_size,
                              hipStream_t stream) {
    const float* x   = (const float*)d_in[0];
    const int*   ei  = (const int*)d_in[1];
    const float* W1  = (const float*)d_in[2];
    const float* a1s = (const float*)d_in[3];
    const float* a1d = (const float*)d_in[4];
    const float* b1  = (const float*)d_in[5];
    const float* W2  = (const float*)d_in[6];
    const float* a2s = (const float*)d_in[7];
    const float* a2d = (const float*)d_in[8];
    const float* b2  = (const float*)d_in[9];
    const float* W3  = (const float*)d_in[10];
    const float* a3s = (const float*)d_in[11];
    const float* a3d = (const float*)d_in[12];
    const float* b3  = (const float*)d_in[13];
    const float* g1  = (const float*)d_in[14];
    const float* be1 = (const float*)d_in[15];
    const float* g2  = (const float*)d_in[16];
    const float* be2 = (const float*)d_in[17];
    const float* g3  = (const float*)d_in[18];
    const float* be3 = (const float*)d_in[19];
    const float* Wh  = (const float*)d_in[20];
    const float* bh  = (const float*)d_in[21];
    float* out = (float*)d_out;

    char* ws = (char*)d_ws;
    size_t off = 0;
    auto alloc = [&](size_t bytes) -> void* {
        void* p = ws + off;
        off += (bytes + 255) & ~(size_t)255;
        return p;
    };
    int*   row_ptr = (int*)alloc((N_NODES + 1) * sizeof(int));
    int*   cursor  = (int*)alloc((N_NODES + 1) * sizeof(int));
    int*   bsum    = (int*)alloc(256 * sizeof(int));
    int*   col_src = (int*)alloc((size_t)ET * sizeof(int));
    float* es      = (float*)alloc((size_t)N_NODES * 8 * sizeof(float));
    float* ed      = (float*)alloc((size_t)N_NODES * 8 * sizeof(float));
    float* bufA    = (float*)alloc((size_t)N_NODES * 128 * sizeof(float));  // h2 pre (also aggx alias)
    float* bufB    = (float*)alloc((size_t)N_NODES * 128 * sizeof(float));  // h2' post
    float* bufC    = (float*)alloc((size_t)N_NODES * 32 * sizeof(float));   // h3 pre
    __hip_bfloat16* Ah   = (__hip_bfloat16*)alloc((size_t)MPAD * 512 * sizeof(__hip_bfloat16));
    __hip_bfloat16* Al   = (__hip_bfloat16*)alloc((size_t)MPAD * 512 * sizeof(__hip_bfloat16));
    __hip_bfloat16* W2Th = (__hip_bfloat16*)alloc((size_t)128 * 512 * sizeof(__hip_bfloat16));
    __hip_bfloat16* W2Tl = (__hip_bfloat16*)alloc((size_t)128 * 512 * sizeof(__hip_bfloat16));
    float* M1 = (float*)(ws + ((ws_size - 1024) & ~(size_t)255));
    float* aggx = bufA;   // [N,72] — bufA dead until gemm2 output

    // ---- CSR build (dst-sorted), shared by all three layers ----
    zero_int_kernel<<<(N_NODES + 1 + 255) / 256, 256, 0, stream>>>(cursor, N_NODES + 1);
    hist_kernel<<<(ET + 255) / 256, 256, 0, stream>>>(ei, cursor);
    scan1_kernel<<<NBLK_SCAN, 256, 0, stream>>>(cursor, row_ptr, bsum);
    scan2_kernel<<<1, 256, 0, stream>>>(bsum, NBLK_SCAN);
    scan3_kernel<<<NBLK_SCAN, 256, 0, stream>>>(row_ptr, bsum, cursor);
    fill_kernel<<<(ET + 255) / 256, 256, 0, stream>>>(ei, cursor, col_src);

    // ---- layer 1: GAT(9 -> 8x64, concat) + BN + ELU, aggregated in x-space ----
    prep_attn1_kernel<<<1, 256, 0, stream>>>(W1, a1s, a1d, M1);
    es_ed1_kernel<<<(N_NODES + 255) / 256, 256, 0, stream>>>(x, M1, es, ed);
    agg1_kernel<<<N_NODES, 128, 0, stream>>>(x, row_ptr, col_src, es, ed, aggx);
    transform1_kernel<<<1024, 512, 0, stream>>>(aggx, W1, b1, g1, be1, Ah, Al);

    // ---- layer 2: GAT(512 -> 4x32, concat) + BN + ELU ----
    prep_w2_kernel<<<256, 256, 0, stream>>>(W2, W2Th, W2Tl);
    gemm2_mfma_kernel<<<MPAD / 128, 256, 0, stream>>>(Ah, Al, W2Th, W2Tl, bufA);
    attn_dots_kernel<4, 32><<<(N_NODES * 4 + 255) / 256, 256, 0, stream>>>(bufA, a2s, a2d, es, ed);
    gat_agg_kernel<4, 32><<<N_NODES, 128, 0, stream>>>(bufA, row_ptr, col_src, es, ed,
                                                       b2, g2, be2, bufB);

    // ---- layer 3: GAT(128 -> 1x32, mean) + BN + ELU ----
    gemm_kernel<1><<<dim3((N_NODES + 63) / 64, 1), 256, 0, stream>>>(bufB, W3, bufC, N_NODES, 128, 32);
    attn_dots_kernel<1, 32><<<(N_NODES + 255) / 256, 256, 0, stream>>>(bufC, a3s, a3d, es, ed);
    gat_agg_kernel<1, 32><<<N_NODES, 64, 0, stream>>>(bufC, row_ptr, col_src, es, ed,
                                                      b3, g3, be3, bufA);

    // ---- head ----
    head_kernel<<<(N_NODES + 255) / 256, 256, 0, stream>>>(bufA, Wh, bh, out);
}

// Round 5
// 457.443 us; speedup vs baseline: 2.0693x; 1.0455x over previous
//
#include <hip/hip_runtime.h>
#include <hip/hip_bf16.h>
#include <math.h>

#define N_NODES 50000
#define E_EDGES 800000
#define ET (E_EDGES + N_NODES)   // edges + self loops = 850000
#define NBLK_SCAN ((N_NODES + 255) / 256)   // 196
#define MPAD 50048               // 391 * 128
#define NPB_T1 16                // nodes per block in transform1

typedef __attribute__((ext_vector_type(8))) short bf16x8;
typedef __attribute__((ext_vector_type(4))) float f32x4;

// ---------------- CSR build ----------------

__global__ void zero_int_kernel(int* __restrict__ p, int n) {
    int i = blockIdx.x * blockDim.x + threadIdx.x;
    if (i < n) p[i] = 0;
}

__global__ void hist_kernel(const int* __restrict__ ei, int* __restrict__ cnt) {
    int e = blockIdx.x * blockDim.x + threadIdx.x;
    if (e < ET) {
        int d = (e < E_EDGES) ? ei[E_EDGES + e] : (e - E_EDGES);
        atomicAdd(&cnt[d], 1);
    }
}

__global__ void scan1_kernel(const int* __restrict__ cnt, int* __restrict__ rp,
                             int* __restrict__ bsum) {
    __shared__ int s[256];
    int i = blockIdx.x * 256 + threadIdx.x;
    int v = (i < N_NODES) ? cnt[i] : 0;
    s[threadIdx.x] = v;
    __syncthreads();
    for (int off = 1; off < 256; off <<= 1) {
        int t = (threadIdx.x >= off) ? s[threadIdx.x - off] : 0;
        __syncthreads();
        s[threadIdx.x] += t;
        __syncthreads();
    }
    if (i < N_NODES) rp[i + 1] = s[threadIdx.x];
    if (threadIdx.x == 255) bsum[blockIdx.x] = s[255];
}

__global__ void scan2_kernel(int* __restrict__ bsum, int nb) {
    __shared__ int s[256];
    int v = (threadIdx.x < nb) ? bsum[threadIdx.x] : 0;
    s[threadIdx.x] = v;
    __syncthreads();
    for (int off = 1; off < 256; off <<= 1) {
        int t = (threadIdx.x >= off) ? s[threadIdx.x - off] : 0;
        __syncthreads();
        s[threadIdx.x] += t;
        __syncthreads();
    }
    if (threadIdx.x < nb) bsum[threadIdx.x] = (threadIdx.x == 0) ? 0 : s[threadIdx.x - 1];
}

__global__ void scan3_kernel(int* __restrict__ rp, const int* __restrict__ bsum,
                             int* __restrict__ cursor) {
    int i = blockIdx.x * 256 + threadIdx.x;
    if (i == 0) rp[0] = 0;
    if (i < N_NODES) {
        int incl = rp[i + 1] + bsum[i >> 8];
        rp[i + 1] = incl;
        cursor[i] = incl - cursor[i];
    }
}

__global__ void fill_kernel(const int* __restrict__ ei, int* __restrict__ cursor,
                            int* __restrict__ col) {
    int e = blockIdx.x * blockDim.x + threadIdx.x;
    if (e < ET) {
        int s_, d;
        if (e < E_EDGES) { s_ = ei[e]; d = ei[E_EDGES + e]; }
        else             { s_ = e - E_EDGES; d = s_; }
        int p = atomicAdd(&cursor[d], 1);
        col[p] = s_;
    }
}

// ---------------- layer-1 specialized path (aggregate in x-space, K=9) ----------------

__global__ void prep_attn1_kernel(const float* __restrict__ W1,
                                  const float* __restrict__ a1s,
                                  const float* __restrict__ a1d,
                                  float* __restrict__ M) {
    int t = threadIdx.x;
    if (t < 144) {
        int which = t / 72, idx = t % 72, k = idx / 8, h = idx % 8;
        const float* a = which ? a1d : a1s;
        float s = 0.f;
        for (int c = 0; c < 64; c++) s += W1[k * 512 + h * 64 + c] * a[h * 64 + c];
        M[t] = s;
    }
}

__global__ void es_ed1_kernel(const float* __restrict__ x, const float* __restrict__ M,
                              float* __restrict__ es, float* __restrict__ ed) {
    int n = blockIdx.x * blockDim.x + threadIdx.x;
    if (n >= N_NODES) return;
    float xr[9];
#pragma unroll
    for (int k = 0; k < 9; k++) xr[k] = x[(size_t)n * 9 + k];
#pragma unroll
    for (int h = 0; h < 8; h++) {
        float s1 = 0.f, s2 = 0.f;
#pragma unroll
        for (int k = 0; k < 9; k++) {
            s1 += xr[k] * M[k * 8 + h];
            s2 += xr[k] * M[72 + k * 8 + h];
        }
        es[(size_t)n * 8 + h] = s1;
        ed[(size_t)n * 8 + h] = s2;
    }
}

// per-dst: online softmax over in-edges + aggregate x rows (9 floats) per head.
__global__ __launch_bounds__(128) void agg1_kernel(const float* __restrict__ x,
        const int* __restrict__ rp, const int* __restrict__ col,
        const float* __restrict__ es, const float* __restrict__ ed,
        float* __restrict__ aggx) {
    __shared__ int   s_src[64];
    __shared__ float s_x[64][9];
    __shared__ float s_es[64][8];
    __shared__ float s_w[8][64];
    __shared__ float s_m[8], s_den[8], s_scale[8], s_ed[8];
    int n = blockIdx.x, tid = threadIdx.x;
    int start = rp[n], end = rp[n + 1];
    if (tid < 8) { s_m[tid] = -INFINITY; s_den[tid] = 0.f; s_ed[tid] = ed[(size_t)n * 8 + tid]; }
    __syncthreads();
    float acc = 0.f;
    int ghh = tid >> 4, glane = tid & 15;
    for (int cs = start; cs < end; cs += 64) {
        int cnt = min(64, end - cs);
        if (tid < cnt) s_src[tid] = col[cs + tid];
        __syncthreads();
        for (int q = tid; q < cnt * 9; q += 128) {
            int e = q / 9, k = q - e * 9;
            s_x[e][k] = x[(size_t)s_src[e] * 9 + k];
        }
        for (int q = tid; q < cnt * 8; q += 128) {
            int e = q >> 3, h = q & 7;
            s_es[e][h] = es[(size_t)s_src[e] * 8 + h];
        }
        __syncthreads();
        float lmax = -INFINITY;
        for (int e = glane; e < cnt; e += 16) {
            float l = s_es[e][ghh] + s_ed[ghh];
            l = (l > 0.f) ? l : 0.2f * l;
            s_w[ghh][e] = l;
            lmax = fmaxf(lmax, l);
        }
#pragma unroll
        for (int off = 8; off > 0; off >>= 1) lmax = fmaxf(lmax, __shfl_xor(lmax, off));
        float mold = s_m[ghh];
        float nm = fmaxf(mold, lmax);
        float fac = __expf(mold - nm);
        float psum = 0.f;
        for (int e = glane; e < cnt; e += 16) {
            float w = __expf(s_w[ghh][e] - nm);
            s_w[ghh][e] = w;
            psum += w;
        }
#pragma unroll
        for (int off = 8; off > 0; off >>= 1) psum += __shfl_xor(psum, off);
        if (glane == 0) { s_den[ghh] = s_den[ghh] * fac + psum; s_m[ghh] = nm; s_scale[ghh] = fac; }
        __syncthreads();
        if (tid < 72) {
            int hh = tid / 9, k = tid - hh * 9;
            float a = acc * s_scale[hh];
            for (int e = 0; e < cnt; e++) a += s_w[hh][e] * s_x[e][k];
            acc = a;
        }
        __syncthreads();
    }
    if (tid < 72) {
        int hh = tid / 9;
        aggx[(size_t)n * 72 + tid] = acc / s_den[hh];
    }
}

// out = ELU(BN( aggx@W1 + b1 )) -> bf16 hi/lo split [MPAD,512].
// 16 nodes per block, 256 threads, 2 channels/thread, W1 pair in registers.
__global__ __launch_bounds__(256) void transform1_kernel(const float* __restrict__ aggx,
        const float* __restrict__ W1, const float* __restrict__ b1,
        const float* __restrict__ g1, const float* __restrict__ be1,
        __hip_bfloat16* __restrict__ Ah, __hip_bfloat16* __restrict__ Al) {
    __shared__ float s_a[NPB_T1 * 72];
    int tid = threadIdx.x;
    int n0 = blockIdx.x * NPB_T1;
    int nn = min(NPB_T1, N_NODES - n0);
    for (int q = tid; q < nn * 72; q += 256) s_a[q] = aggx[(size_t)n0 * 72 + q];
    int c0 = tid * 2;
    int hh = c0 >> 6;
    float2 wv[9];
#pragma unroll
    for (int k = 0; k < 9; k++) wv[k] = *(const float2*)&W1[k * 512 + c0];
    float2 bv = *(const float2*)&b1[c0];
    float2 gv = *(const float2*)&g1[c0];
    float2 ev = *(const float2*)&be1[c0];
    float gs0 = gv.x / sqrtf(1.00001f), gs1 = gv.y / sqrtf(1.00001f);
    __syncthreads();
    for (int i = 0; i < nn; i++) {
        const float* ar = &s_a[i * 72 + hh * 9];
        float v0 = bv.x, v1 = bv.y;
#pragma unroll
        for (int k = 0; k < 9; k++) { float a = ar[k]; v0 += a * wv[k].x; v1 += a * wv[k].y; }
        v0 = v0 * gs0 + ev.x;
        v1 = v1 * gs1 + ev.y;
        v0 = (v0 > 0.f) ? v0 : expm1f(v0);
        v1 = (v1 > 0.f) ? v1 : expm1f(v1);
        __hip_bfloat16 h0 = __float2bfloat16(v0), h1 = __float2bfloat16(v1);
        float r0 = v0 - __bfloat162float(h0), r1 = v1 - __bfloat162float(h1);
        size_t base = (size_t)(n0 + i) * 512 + c0;
        __hip_bfloat162 hp; hp.x = h0; hp.y = h1;
        __hip_bfloat162 lp; lp.x = __float2bfloat16(r0); lp.y = __float2bfloat16(r1);
        *(__hip_bfloat162*)&Ah[base] = hp;
        *(__hip_bfloat162*)&Al[base] = lp;
    }
}

// W2 [512][128] fp32 -> W2^T hi/lo [128][512] bf16
__global__ void prep_w2_kernel(const float* __restrict__ W2,
                               __hip_bfloat16* __restrict__ Wh,
                               __hip_bfloat16* __restrict__ Wl) {
    int t = blockIdx.x * 256 + threadIdx.x;
    if (t < 512 * 128) {
        int k = t >> 7, c = t & 127;
        float v = W2[t];
        __hip_bfloat16 hi = __float2bfloat16(v);
        float r = v - __bfloat162float(hi);
        Wh[c * 512 + k] = hi;
        Wl[c * 512 + k] = __float2bfloat16(r);
    }
}

// ---------------- layer-2 GEMM via MFMA: C[N,128] = A[N,512] @ W2 ----------------

__global__ __launch_bounds__(256) void gemm2_mfma_kernel(
        const __hip_bfloat16* __restrict__ Ah, const __hip_bfloat16* __restrict__ Al,
        const __hip_bfloat16* __restrict__ Wh, const __hip_bfloat16* __restrict__ Wl,
        float* __restrict__ C) {
    __shared__ short lds[32768];   // 64 KB: Ah | Al | Wh | Wl, 8192 shorts each
    int tid = threadIdx.x;
    int wv = tid >> 6;
    int lane = tid & 63;
    int lrow = lane & 15, kgrp = lane >> 4;
    int m0 = blockIdx.x * 128;

    f32x4 acc[2][8];
#pragma unroll
    for (int m = 0; m < 2; m++)
#pragma unroll
        for (int n = 0; n < 8; n++) acc[m][n] = (f32x4){0.f, 0.f, 0.f, 0.f};

    for (int kk = 0; kk < 512; kk += 64) {
#pragma unroll
        for (int tI = 0; tI < 4; tI++) {
            const __hip_bfloat16* src = (tI == 0) ? Ah : (tI == 1) ? Al : (tI == 2) ? Wh : Wl;
            int rowBase = (tI < 2) ? m0 : 0;
#pragma unroll
            for (int i = 0; i < 4; i++) {
                int gid = tid + 256 * i;
                int row = gid >> 3, kg = gid & 7;
                bf16x8 v = *(const bf16x8*)(src + (size_t)(rowBase + row) * 512 + kk + kg * 8);
                *(bf16x8*)(lds + tI * 8192 + row * 64 + ((kg ^ (row & 7)) << 3)) = v;
            }
        }
        __syncthreads();
#pragma unroll
        for (int ks = 0; ks < 2; ks++) {
            bf16x8 ah[2], al[2];
#pragma unroll
            for (int m = 0; m < 2; m++) {
                int row = wv * 32 + m * 16 + lrow;
                int kg = ks * 4 + kgrp;
                int so = row * 64 + ((kg ^ (row & 7)) << 3);
                ah[m] = *(const bf16x8*)(lds + so);
                al[m] = *(const bf16x8*)(lds + 8192 + so);
            }
#pragma unroll
            for (int n = 0; n < 8; n++) {
                int colr = n * 16 + lrow;
                int kg = ks * 4 + kgrp;
                int so = colr * 64 + ((kg ^ (colr & 7)) << 3);
                bf16x8 wh = *(const bf16x8*)(lds + 16384 + so);
                bf16x8 wl = *(const bf16x8*)(lds + 24576 + so);
#pragma unroll
                for (int m = 0; m < 2; m++) {
                    acc[m][n] = __builtin_amdgcn_mfma_f32_16x16x32_bf16(ah[m], wh, acc[m][n], 0, 0, 0);
                    acc[m][n] = __builtin_amdgcn_mfma_f32_16x16x32_bf16(al[m], wh, acc[m][n], 0, 0, 0);
                    acc[m][n] = __builtin_amdgcn_mfma_f32_16x16x32_bf16(ah[m], wl, acc[m][n], 0, 0, 0);
                }
            }
        }
        __syncthreads();
    }
#pragma unroll
    for (int m = 0; m < 2; m++) {
#pragma unroll
        for (int n = 0; n < 8; n++) {
#pragma unroll
            for (int r = 0; r < 4; r++) {
                int row = m0 + wv * 32 + m * 16 + (lane >> 4) * 4 + r;
                int colc = n * 16 + (lane & 15);
                if (row < N_NODES) C[(size_t)row * 128 + colc] = acc[m][n][r];
            }
        }
    }
}

// ---------------- small GEMM (layer 3): C[M,Nd] = A[M,K]@B[K,Nd] ----------------

template <int TN>
__global__ __launch_bounds__(256) void gemm_kernel(
        const float* __restrict__ A, const float* __restrict__ B,
        float* __restrict__ C, int M, int K, int Nd) {
    constexpr int BM = 64, BK = 16;
    constexpr int BN = 32 * TN;
    __shared__ float As[BM * BK];
    __shared__ float Bs[BK * BN];
    int tid = threadIdx.x;
    int m0 = blockIdx.x * BM;
    int n0 = blockIdx.y * BN;
    int tc = tid & 31;
    int tr = tid >> 5;
    float acc[8][TN];
#pragma unroll
    for (int i = 0; i < 8; i++)
#pragma unroll
        for (int j = 0; j < TN; j++) acc[i][j] = 0.f;

    for (int kk = 0; kk < K; kk += BK) {
#pragma unroll
        for (int l = 0; l < (BM * BK) / 256; l++) {
            int e = tid + 256 * l;
            int r = e >> 4, k = e & 15;
            float v = 0.f;
            if (m0 + r < M && kk + k < K) v = A[(size_t)(m0 + r) * K + kk + k];
            As[e] = v;
        }
#pragma unroll
        for (int l = 0; l < (BK * BN) / 256; l++) {
            int e = tid + 256 * l;
            int r = e / BN, c = e % BN;
            float v = 0.f;
            if (kk + r < K) v = B[(size_t)(kk + r) * Nd + n0 + c];
            Bs[e] = v;
        }
        __syncthreads();
#pragma unroll
        for (int k = 0; k < BK; k++) {
            float bv[TN];
#pragma unroll
            for (int j = 0; j < TN; j++) bv[j] = Bs[k * BN + tc * TN + j];
#pragma unroll
            for (int i = 0; i < 8; i++) {
                float a = As[(tr * 8 + i) * BK + k];
#pragma unroll
                for (int j = 0; j < TN; j++) acc[i][j] += a * bv[j];
            }
        }
        __syncthreads();
    }
#pragma unroll
    for (int i = 0; i < 8; i++) {
        int r = m0 + tr * 8 + i;
        if (r < M) {
#pragma unroll
            for (int j = 0; j < TN; j++)
                C[(size_t)r * Nd + n0 + tc * TN + j] = acc[i][j];
        }
    }
}

// ---------------- per-(node,head) attention dots ----------------

template <int H, int C>
__global__ void attn_dots_kernel(const float* __restrict__ hin,
                                 const float* __restrict__ as_, const float* __restrict__ ad_,
                                 float* __restrict__ es, float* __restrict__ ed) {
    int t = blockIdx.x * blockDim.x + threadIdx.x;
    if (t >= N_NODES * H) return;
    int n = t / H, hh = t % H;
    const float* row = hin + (size_t)n * (H * C) + hh * C;
    float s1 = 0.f, s2 = 0.f;
    for (int c = 0; c < C; c++) {
        float v = row[c];
        s1 += v * as_[hh * C + c];
        s2 += v * ad_[hh * C + c];
    }
    es[t] = s1;
    ed[t] = s2;
}

// ---------------- per-dst online-softmax + float4 group-gather + bias/BN/ELU ----------------
// RT = HC/4 threads cover one row (float4/thread); G = BLK/RT edge groups run
// concurrently; cross-group partials reduced once in LDS at the end.

template <int H, int C>
__global__ __launch_bounds__((H * C < 64) ? 64 : H * C) void gat_agg_kernel(
        const float* __restrict__ hin,
        const int* __restrict__ rp, const int* __restrict__ col,
        const float* __restrict__ es, const float* __restrict__ ed,
        const float* __restrict__ bias, const float* __restrict__ gg,
        const float* __restrict__ bb,
        float* __restrict__ out) {
    constexpr int HC  = H * C;
    constexpr int BLK = (HC < 64) ? 64 : HC;
    constexpr int LPH = (BLK / H > 64) ? 64 : (BLK / H);
    constexpr int RT  = HC / 4;    // threads per row
    constexpr int G   = BLK / RT;  // concurrent edge groups
    constexpr int CH  = 64;
    __shared__ int   s_src[CH];
    __shared__ float s_w[H][CH];
    __shared__ float s_red[G][HC];
    __shared__ float s_m[H], s_den[H], s_scale[H], s_ed[H];

    int n = blockIdx.x;
    int tid = threadIdx.x;
    int start = rp[n], end = rp[n + 1];
    if (tid < H) {
        s_m[tid] = -INFINITY;
        s_den[tid] = 0.f;
        s_ed[tid] = ed[(size_t)n * H + tid];
    }
    __syncthreads();

    int ghh = tid / LPH, glane = tid % LPH;
    int g = tid / RT, rl = tid % RT;
    int hh2 = (rl * 4) / C;        // head owning my 4 channels
    float ax = 0.f, ay = 0.f, az = 0.f, aw = 0.f;

    for (int cs = start; cs < end; cs += CH) {
        int cnt = min(CH, end - cs);
        if (tid < cnt) s_src[tid] = col[cs + tid];
        __syncthreads();

        // ---- softmax bookkeeping (LPH lanes per head) ----
        {
            float lmax = -INFINITY;
            for (int e = glane; e < cnt; e += LPH) {
                float l = es[(size_t)s_src[e] * H + ghh] + s_ed[ghh];
                l = (l > 0.f) ? l : 0.2f * l;
                s_w[ghh][e] = l;
                lmax = fmaxf(lmax, l);
            }
#pragma unroll
            for (int off = LPH >> 1; off > 0; off >>= 1)
                lmax = fmaxf(lmax, __shfl_xor(lmax, off));
            float mold = s_m[ghh];
            float nm = fmaxf(mold, lmax);
            float fac = __expf(mold - nm);
            float psum = 0.f;
            for (int e = glane; e < cnt; e += LPH) {
                float w = __expf(s_w[ghh][e] - nm);
                s_w[ghh][e] = w;
                psum += w;
            }
#pragma unroll
            for (int off = LPH >> 1; off > 0; off >>= 1)
                psum += __shfl_xor(psum, off);
            if (glane == 0) {
                s_den[ghh] = s_den[ghh] * fac + psum;
                s_m[ghh] = nm;
                s_scale[ghh] = fac;
            }
        }
        __syncthreads();

        // ---- float4 gather, G edges concurrently, 2-deep unroll ----
        {
            float fac = s_scale[hh2];
            float bx = ax * fac, by = ay * fac, bz = az * fac, bw = aw * fac;
            float cx = 0.f, cy = 0.f, cz = 0.f, cw = 0.f;
            int e = g;
            for (; e + G < cnt; e += 2 * G) {
                float w0 = s_w[hh2][e];
                float w1 = s_w[hh2][e + G];
                float4 v0 = *(const float4*)&hin[(size_t)s_src[e] * HC + rl * 4];
                float4 v1 = *(const float4*)&hin[(size_t)s_src[e + G] * HC + rl * 4];
                bx += w0 * v0.x; by += w0 * v0.y; bz += w0 * v0.z; bw += w0 * v0.w;
                cx += w1 * v1.x; cy += w1 * v1.y; cz += w1 * v1.z; cw += w1 * v1.w;
            }
            if (e < cnt) {
                float w0 = s_w[hh2][e];
                float4 v0 = *(const float4*)&hin[(size_t)s_src[e] * HC + rl * 4];
                bx += w0 * v0.x; by += w0 * v0.y; bz += w0 * v0.z; bw += w0 * v0.w;
            }
            ax = bx + cx; ay = by + cy; az = bz + cz; aw = bw + cw;
        }
        __syncthreads();
    }

    // ---- cross-group reduce + epilogue ----
    s_red[g][rl * 4 + 0] = ax;
    s_red[g][rl * 4 + 1] = ay;
    s_red[g][rl * 4 + 2] = az;
    s_red[g][rl * 4 + 3] = aw;
    __syncthreads();
    if (tid < HC) {
        int hh = tid / C;
        float res = 0.f;
#pragma unroll
        for (int q = 0; q < G; q++) res += s_red[q][tid];
        res /= s_den[hh];
        res += bias[tid];
        res = res * (gg[tid] / sqrtf(1.00001f)) + bb[tid];
        res = (res > 0.f) ? res : expm1f(res);
        out[(size_t)n * HC + tid] = res;
    }
}

// ---------------- final linear head [N,32] @ [32,1] + bh ----------------

__global__ void head_kernel(const float* __restrict__ h3, const float* __restrict__ Wh,
                            const float* __restrict__ bh, float* __restrict__ out) {
    int n = blockIdx.x * blockDim.x + threadIdx.x;
    if (n < N_NODES) {
        float s = bh[0];
        const float* row = h3 + (size_t)n * 32;
#pragma unroll
        for (int c = 0; c < 32; c++) s += row[c] * Wh[c];
        out[n] = s;
    }
}

// ---------------- launch ----------------

extern "C" void kernel_launch(void* const* d_in, const int* in_sizes, int n_in,
                              void* d_out, int out_size, void* d_ws, size_t ws_size,
                              hipStream_t stream) {
    const float* x   = (const float*)d_in[0];
    const int*   ei  = (const int*)d_in[1];
    const float* W1  = (const float*)d_in[2];
    const float* a1s = (const float*)d_in[3];
    const float* a1d = (const float*)d_in[4];
    const float* b1  = (const float*)d_in[5];
    const float* W2  = (const float*)d_in[6];
    const float* a2s = (const float*)d_in[7];
    const float* a2d = (const float*)d_in[8];
    const float* b2  = (const float*)d_in[9];
    const float* W3  = (const float*)d_in[10];
    const float* a3s = (const float*)d_in[11];
    const float* a3d = (const float*)d_in[12];
    const float* b3  = (const float*)d_in[13];
    const float* g1  = (const float*)d_in[14];
    const float* be1 = (const float*)d_in[15];
    const float* g2  = (const float*)d_in[16];
    const float* be2 = (const float*)d_in[17];
    const float* g3  = (const float*)d_in[18];
    const float* be3 = (const float*)d_in[19];
    const float* Wh  = (const float*)d_in[20];
    const float* bh  = (const float*)d_in[21];
    float* out = (float*)d_out;

    char* ws = (char*)d_ws;
    size_t off = 0;
    auto alloc = [&](size_t bytes) -> void* {
        void* p = ws + off;
        off += (bytes + 255) & ~(size_t)255;
        return p;
    };
    int*   row_ptr = (int*)alloc((N_NODES + 1) * sizeof(int));
    int*   cursor  = (int*)alloc((N_NODES + 1) * sizeof(int));
    int*   bsum    = (int*)alloc(256 * sizeof(int));
    int*   col_src = (int*)alloc((size_t)ET * sizeof(int));
    float* es      = (float*)alloc((size_t)N_NODES * 8 * sizeof(float));
    float* ed      = (float*)alloc((size_t)N_NODES * 8 * sizeof(float));
    float* bufA    = (float*)alloc((size_t)N_NODES * 128 * sizeof(float));  // h2 pre (also aggx alias)
    float* bufB    = (float*)alloc((size_t)N_NODES * 128 * sizeof(float));  // h2' post
    float* bufC    = (float*)alloc((size_t)N_NODES * 32 * sizeof(float));   // h3 pre
    __hip_bfloat16* Ah   = (__hip_bfloat16*)alloc((size_t)MPAD * 512 * sizeof(__hip_bfloat16));
    __hip_bfloat16* Al   = (__hip_bfloat16*)alloc((size_t)MPAD * 512 * sizeof(__hip_bfloat16));
    __hip_bfloat16* W2Th = (__hip_bfloat16*)alloc((size_t)128 * 512 * sizeof(__hip_bfloat16));
    __hip_bfloat16* W2Tl = (__hip_bfloat16*)alloc((size_t)128 * 512 * sizeof(__hip_bfloat16));
    float* M1 = (float*)(ws + ((ws_size - 1024) & ~(size_t)255));
    float* aggx = bufA;   // [N,72] — bufA dead until gemm2 output

    // ---- CSR build (dst-sorted), shared by all three layers ----
    zero_int_kernel<<<(N_NODES + 1 + 255) / 256, 256, 0, stream>>>(cursor, N_NODES + 1);
    hist_kernel<<<(ET + 255) / 256, 256, 0, stream>>>(ei, cursor);
    scan1_kernel<<<NBLK_SCAN, 256, 0, stream>>>(cursor, row_ptr, bsum);
    scan2_kernel<<<1, 256, 0, stream>>>(bsum, NBLK_SCAN);
    scan3_kernel<<<NBLK_SCAN, 256, 0, stream>>>(row_ptr, bsum, cursor);
    fill_kernel<<<(ET + 255) / 256, 256, 0, stream>>>(ei, cursor, col_src);

    // ---- layer 1: GAT(9 -> 8x64, concat) + BN + ELU, aggregated in x-space ----
    prep_attn1_kernel<<<1, 256, 0, stream>>>(W1, a1s, a1d, M1);
    es_ed1_kernel<<<(N_NODES + 255) / 256, 256, 0, stream>>>(x, M1, es, ed);
    agg1_kernel<<<N_NODES, 128, 0, stream>>>(x, row_ptr, col_src, es, ed, aggx);
    transform1_kernel<<<(N_NODES + NPB_T1 - 1) / NPB_T1, 256, 0, stream>>>(aggx, W1, b1, g1, be1, Ah, Al);

    // ---- layer 2: GAT(512 -> 4x32, concat) + BN + ELU ----
    prep_w2_kernel<<<256, 256, 0, stream>>>(W2, W2Th, W2Tl);
    gemm2_mfma_kernel<<<MPAD / 128, 256, 0, stream>>>(Ah, Al, W2Th, W2Tl, bufA);
    attn_dots_kernel<4, 32><<<(N_NODES * 4 + 255) / 256, 256, 0, stream>>>(bufA, a2s, a2d, es, ed);
    gat_agg_kernel<4, 32><<<N_NODES, 128, 0, stream>>>(bufA, row_ptr, col_src, es, ed,
                                                       b2, g2, be2, bufB);

    // ---- layer 3: GAT(128 -> 1x32, mean) + BN + ELU ----
    gemm_kernel<1><<<dim3((N_NODES + 63) / 64, 1), 256, 0, stream>>>(bufB, W3, bufC, N_NODES, 128, 32);
    attn_dots_kernel<1, 32><<<(N_NODES + 255) / 256, 256, 0, stream>>>(bufC, a3s, a3d, es, ed);
    gat_agg_kernel<1, 32><<<N_NODES, 64, 0, stream>>>(bufC, row_ptr, col_src, es, ed,
                                                      b3, g3, be3, bufA);

    // ---- head ----
    head_kernel<<<(N_NODES + 255) / 256, 256, 0, stream>>>(bufA, Wh, bh, out);
}

// Round 6
// 431.845 us; speedup vs baseline: 2.1920x; 1.0593x over previous
//
#include <hip/hip_runtime.h>
#include <hip/hip_bf16.h>
#include <math.h>

#define N_NODES 50000
#define E_EDGES 800000
#define ET (E_EDGES + N_NODES)   // edges + self loops = 850000
#define NBLK_SCAN ((N_NODES + 255) / 256)   // 196
#define MPAD 50048               // 391 * 128
#define NPB_T1 16                // nodes per block in transform1

typedef __attribute__((ext_vector_type(8))) short bf16x8;
typedef __attribute__((ext_vector_type(4))) float f32x4;
typedef __attribute__((ext_vector_type(8))) _Float16 half8;

// ---------------- CSR build ----------------

__global__ void zero_int_kernel(int* __restrict__ p, int n) {
    int i = blockIdx.x * blockDim.x + threadIdx.x;
    if (i < n) p[i] = 0;
}

__global__ void hist_kernel(const int* __restrict__ ei, int* __restrict__ cnt) {
    int e = blockIdx.x * blockDim.x + threadIdx.x;
    if (e < ET) {
        int d = (e < E_EDGES) ? ei[E_EDGES + e] : (e - E_EDGES);
        atomicAdd(&cnt[d], 1);
    }
}

__global__ void scan1_kernel(const int* __restrict__ cnt, int* __restrict__ rp,
                             int* __restrict__ bsum) {
    __shared__ int s[256];
    int i = blockIdx.x * 256 + threadIdx.x;
    int v = (i < N_NODES) ? cnt[i] : 0;
    s[threadIdx.x] = v;
    __syncthreads();
    for (int off = 1; off < 256; off <<= 1) {
        int t = (threadIdx.x >= off) ? s[threadIdx.x - off] : 0;
        __syncthreads();
        s[threadIdx.x] += t;
        __syncthreads();
    }
    if (i < N_NODES) rp[i + 1] = s[threadIdx.x];
    if (threadIdx.x == 255) bsum[blockIdx.x] = s[255];
}

__global__ void scan2_kernel(int* __restrict__ bsum, int nb) {
    __shared__ int s[256];
    int v = (threadIdx.x < nb) ? bsum[threadIdx.x] : 0;
    s[threadIdx.x] = v;
    __syncthreads();
    for (int off = 1; off < 256; off <<= 1) {
        int t = (threadIdx.x >= off) ? s[threadIdx.x - off] : 0;
        __syncthreads();
        s[threadIdx.x] += t;
        __syncthreads();
    }
    if (threadIdx.x < nb) bsum[threadIdx.x] = (threadIdx.x == 0) ? 0 : s[threadIdx.x - 1];
}

__global__ void scan3_kernel(int* __restrict__ rp, const int* __restrict__ bsum,
                             int* __restrict__ cursor) {
    int i = blockIdx.x * 256 + threadIdx.x;
    if (i == 0) rp[0] = 0;
    if (i < N_NODES) {
        int incl = rp[i + 1] + bsum[i >> 8];
        rp[i + 1] = incl;
        cursor[i] = incl - cursor[i];
    }
}

__global__ void fill_kernel(const int* __restrict__ ei, int* __restrict__ cursor,
                            int* __restrict__ col) {
    int e = blockIdx.x * blockDim.x + threadIdx.x;
    if (e < ET) {
        int s_, d;
        if (e < E_EDGES) { s_ = ei[e]; d = ei[E_EDGES + e]; }
        else             { s_ = e - E_EDGES; d = s_; }
        int p = atomicAdd(&cursor[d], 1);
        col[p] = s_;
    }
}

// ---------------- layer-1 specialized path (aggregate in x-space, K=9) ----------------

__global__ void prep_attn1_kernel(const float* __restrict__ W1,
                                  const float* __restrict__ a1s,
                                  const float* __restrict__ a1d,
                                  float* __restrict__ M) {
    int t = threadIdx.x;
    if (t < 144) {
        int which = t / 72, idx = t % 72, k = idx / 8, h = idx % 8;
        const float* a = which ? a1d : a1s;
        float s = 0.f;
        for (int c = 0; c < 64; c++) s += W1[k * 512 + h * 64 + c] * a[h * 64 + c];
        M[t] = s;
    }
}

__global__ void es_ed1_kernel(const float* __restrict__ x, const float* __restrict__ M,
                              float* __restrict__ es, float* __restrict__ ed) {
    int n = blockIdx.x * blockDim.x + threadIdx.x;
    if (n >= N_NODES) return;
    float xr[9];
#pragma unroll
    for (int k = 0; k < 9; k++) xr[k] = x[(size_t)n * 9 + k];
#pragma unroll
    for (int h = 0; h < 8; h++) {
        float s1 = 0.f, s2 = 0.f;
#pragma unroll
        for (int k = 0; k < 9; k++) {
            s1 += xr[k] * M[k * 8 + h];
            s2 += xr[k] * M[72 + k * 8 + h];
        }
        es[(size_t)n * 8 + h] = s1;
        ed[(size_t)n * 8 + h] = s2;
    }
}

// per-dst: online softmax over in-edges + aggregate x rows (9 floats) per head.
__global__ __launch_bounds__(128) void agg1_kernel(const float* __restrict__ x,
        const int* __restrict__ rp, const int* __restrict__ col,
        const float* __restrict__ es, const float* __restrict__ ed,
        float* __restrict__ aggx) {
    __shared__ int   s_src[64];
    __shared__ float s_x[64][9];
    __shared__ float s_es[64][8];
    __shared__ float s_w[8][64];
    __shared__ float s_m[8], s_den[8], s_scale[8], s_ed[8];
    int n = blockIdx.x, tid = threadIdx.x;
    int start = rp[n], end = rp[n + 1];
    if (tid < 8) { s_m[tid] = -INFINITY; s_den[tid] = 0.f; s_ed[tid] = ed[(size_t)n * 8 + tid]; }
    __syncthreads();
    float acc = 0.f;
    int ghh = tid >> 4, glane = tid & 15;
    for (int cs = start; cs < end; cs += 64) {
        int cnt = min(64, end - cs);
        if (tid < cnt) s_src[tid] = col[cs + tid];
        __syncthreads();
        for (int q = tid; q < cnt * 9; q += 128) {
            int e = q / 9, k = q - e * 9;
            s_x[e][k] = x[(size_t)s_src[e] * 9 + k];
        }
        for (int q = tid; q < cnt * 8; q += 128) {
            int e = q >> 3, h = q & 7;
            s_es[e][h] = es[(size_t)s_src[e] * 8 + h];
        }
        __syncthreads();
        float lmax = -INFINITY;
        for (int e = glane; e < cnt; e += 16) {
            float l = s_es[e][ghh] + s_ed[ghh];
            l = (l > 0.f) ? l : 0.2f * l;
            s_w[ghh][e] = l;
            lmax = fmaxf(lmax, l);
        }
#pragma unroll
        for (int off = 8; off > 0; off >>= 1) lmax = fmaxf(lmax, __shfl_xor(lmax, off));
        float mold = s_m[ghh];
        float nm = fmaxf(mold, lmax);
        float fac = __expf(mold - nm);
        float psum = 0.f;
        for (int e = glane; e < cnt; e += 16) {
            float w = __expf(s_w[ghh][e] - nm);
            s_w[ghh][e] = w;
            psum += w;
        }
#pragma unroll
        for (int off = 8; off > 0; off >>= 1) psum += __shfl_xor(psum, off);
        if (glane == 0) { s_den[ghh] = s_den[ghh] * fac + psum; s_m[ghh] = nm; s_scale[ghh] = fac; }
        __syncthreads();
        if (tid < 72) {
            int hh = tid / 9, k = tid - hh * 9;
            float a = acc * s_scale[hh];
            for (int e = 0; e < cnt; e++) a += s_w[hh][e] * s_x[e][k];
            acc = a;
        }
        __syncthreads();
    }
    if (tid < 72) {
        int hh = tid / 9;
        aggx[(size_t)n * 72 + tid] = acc / s_den[hh];
    }
}

// out = ELU(BN( aggx@W1 + b1 )) -> bf16 hi/lo split [MPAD,512].
__global__ __launch_bounds__(256) void transform1_kernel(const float* __restrict__ aggx,
        const float* __restrict__ W1, const float* __restrict__ b1,
        const float* __restrict__ g1, const float* __restrict__ be1,
        __hip_bfloat16* __restrict__ Ah, __hip_bfloat16* __restrict__ Al) {
    __shared__ float s_a[NPB_T1 * 72];
    int tid = threadIdx.x;
    int n0 = blockIdx.x * NPB_T1;
    int nn = min(NPB_T1, N_NODES - n0);
    for (int q = tid; q < nn * 72; q += 256) s_a[q] = aggx[(size_t)n0 * 72 + q];
    int c0 = tid * 2;
    int hh = c0 >> 6;
    float2 wv[9];
#pragma unroll
    for (int k = 0; k < 9; k++) wv[k] = *(const float2*)&W1[k * 512 + c0];
    float2 bv = *(const float2*)&b1[c0];
    float2 gv = *(const float2*)&g1[c0];
    float2 ev = *(const float2*)&be1[c0];
    float gs0 = gv.x / sqrtf(1.00001f), gs1 = gv.y / sqrtf(1.00001f);
    __syncthreads();
    for (int i = 0; i < nn; i++) {
        const float* ar = &s_a[i * 72 + hh * 9];
        float v0 = bv.x, v1 = bv.y;
#pragma unroll
        for (int k = 0; k < 9; k++) { float a = ar[k]; v0 += a * wv[k].x; v1 += a * wv[k].y; }
        v0 = v0 * gs0 + ev.x;
        v1 = v1 * gs1 + ev.y;
        v0 = (v0 > 0.f) ? v0 : expm1f(v0);
        v1 = (v1 > 0.f) ? v1 : expm1f(v1);
        __hip_bfloat16 h0 = __float2bfloat16(v0), h1 = __float2bfloat16(v1);
        float r0 = v0 - __bfloat162float(h0), r1 = v1 - __bfloat162float(h1);
        size_t base = (size_t)(n0 + i) * 512 + c0;
        __hip_bfloat162 hp; hp.x = h0; hp.y = h1;
        __hip_bfloat162 lp; lp.x = __float2bfloat16(r0); lp.y = __float2bfloat16(r1);
        *(__hip_bfloat162*)&Ah[base] = hp;
        *(__hip_bfloat162*)&Al[base] = lp;
    }
}

// W2 [512][128] fp32 -> W2^T hi/lo [128][512] bf16
__global__ void prep_w2_kernel(const float* __restrict__ W2,
                               __hip_bfloat16* __restrict__ Wh,
                               __hip_bfloat16* __restrict__ Wl) {
    int t = blockIdx.x * 256 + threadIdx.x;
    if (t < 512 * 128) {
        int k = t >> 7, c = t & 127;
        float v = W2[t];
        __hip_bfloat16 hi = __float2bfloat16(v);
        float r = v - __bfloat162float(hi);
        Wh[c * 512 + k] = hi;
        Wl[c * 512 + k] = __float2bfloat16(r);
    }
}

// ---------------- layer-2 GEMM via MFMA: h2[N,128] (fp16) = A[N,512] @ W2 ----------------

__global__ __launch_bounds__(256) void gemm2_mfma_kernel(
        const __hip_bfloat16* __restrict__ Ah, const __hip_bfloat16* __restrict__ Al,
        const __hip_bfloat16* __restrict__ Wh, const __hip_bfloat16* __restrict__ Wl,
        _Float16* __restrict__ C) {
    __shared__ short lds[32768];   // 64 KB: Ah | Al | Wh | Wl, 8192 shorts each
    int tid = threadIdx.x;
    int wv = tid >> 6;
    int lane = tid & 63;
    int lrow = lane & 15, kgrp = lane >> 4;
    int m0 = blockIdx.x * 128;

    f32x4 acc[2][8];
#pragma unroll
    for (int m = 0; m < 2; m++)
#pragma unroll
        for (int n = 0; n < 8; n++) acc[m][n] = (f32x4){0.f, 0.f, 0.f, 0.f};

    for (int kk = 0; kk < 512; kk += 64) {
#pragma unroll
        for (int tI = 0; tI < 4; tI++) {
            const __hip_bfloat16* src = (tI == 0) ? Ah : (tI == 1) ? Al : (tI == 2) ? Wh : Wl;
            int rowBase = (tI < 2) ? m0 : 0;
#pragma unroll
            for (int i = 0; i < 4; i++) {
                int gid = tid + 256 * i;
                int row = gid >> 3, kg = gid & 7;
                bf16x8 v = *(const bf16x8*)(src + (size_t)(rowBase + row) * 512 + kk + kg * 8);
                *(bf16x8*)(lds + tI * 8192 + row * 64 + ((kg ^ (row & 7)) << 3)) = v;
            }
        }
        __syncthreads();
#pragma unroll
        for (int ks = 0; ks < 2; ks++) {
            bf16x8 ah[2], al[2];
#pragma unroll
            for (int m = 0; m < 2; m++) {
                int row = wv * 32 + m * 16 + lrow;
                int kg = ks * 4 + kgrp;
                int so = row * 64 + ((kg ^ (row & 7)) << 3);
                ah[m] = *(const bf16x8*)(lds + so);
                al[m] = *(const bf16x8*)(lds + 8192 + so);
            }
#pragma unroll
            for (int n = 0; n < 8; n++) {
                int colr = n * 16 + lrow;
                int kg = ks * 4 + kgrp;
                int so = colr * 64 + ((kg ^ (colr & 7)) << 3);
                bf16x8 wh = *(const bf16x8*)(lds + 16384 + so);
                bf16x8 wl = *(const bf16x8*)(lds + 24576 + so);
#pragma unroll
                for (int m = 0; m < 2; m++) {
                    acc[m][n] = __builtin_amdgcn_mfma_f32_16x16x32_bf16(ah[m], wh, acc[m][n], 0, 0, 0);
                    acc[m][n] = __builtin_amdgcn_mfma_f32_16x16x32_bf16(al[m], wh, acc[m][n], 0, 0, 0);
                    acc[m][n] = __builtin_amdgcn_mfma_f32_16x16x32_bf16(ah[m], wl, acc[m][n], 0, 0, 0);
                }
            }
        }
        __syncthreads();
    }
#pragma unroll
    for (int m = 0; m < 2; m++) {
#pragma unroll
        for (int n = 0; n < 8; n++) {
#pragma unroll
            for (int r = 0; r < 4; r++) {
                int row = m0 + wv * 32 + m * 16 + (lane >> 4) * 4 + r;
                int colc = n * 16 + (lane & 15);
                if (row < N_NODES) C[(size_t)row * 128 + colc] = (_Float16)acc[m][n][r];
            }
        }
    }
}

// ---------------- small GEMM (layer 3): C[M,Nd] fp16 = A[M,K]@B[K,Nd] ----------------

template <int TN>
__global__ __launch_bounds__(256) void gemm_h_kernel(
        const float* __restrict__ A, const float* __restrict__ B,
        _Float16* __restrict__ C, int M, int K, int Nd) {
    constexpr int BM = 64, BK = 16;
    constexpr int BN = 32 * TN;
    __shared__ float As[BM * BK];
    __shared__ float Bs[BK * BN];
    int tid = threadIdx.x;
    int m0 = blockIdx.x * BM;
    int n0 = blockIdx.y * BN;
    int tc = tid & 31;
    int tr = tid >> 5;
    float acc[8][TN];
#pragma unroll
    for (int i = 0; i < 8; i++)
#pragma unroll
        for (int j = 0; j < TN; j++) acc[i][j] = 0.f;

    for (int kk = 0; kk < K; kk += BK) {
#pragma unroll
        for (int l = 0; l < (BM * BK) / 256; l++) {
            int e = tid + 256 * l;
            int r = e >> 4, k = e & 15;
            float v = 0.f;
            if (m0 + r < M && kk + k < K) v = A[(size_t)(m0 + r) * K + kk + k];
            As[e] = v;
        }
#pragma unroll
        for (int l = 0; l < (BK * BN) / 256; l++) {
            int e = tid + 256 * l;
            int r = e / BN, c = e % BN;
            float v = 0.f;
            if (kk + r < K) v = B[(size_t)(kk + r) * Nd + n0 + c];
            Bs[e] = v;
        }
        __syncthreads();
#pragma unroll
        for (int k = 0; k < BK; k++) {
            float bv[TN];
#pragma unroll
            for (int j = 0; j < TN; j++) bv[j] = Bs[k * BN + tc * TN + j];
#pragma unroll
            for (int i = 0; i < 8; i++) {
                float a = As[(tr * 8 + i) * BK + k];
#pragma unroll
                for (int j = 0; j < TN; j++) acc[i][j] += a * bv[j];
            }
        }
        __syncthreads();
    }
#pragma unroll
    for (int i = 0; i < 8; i++) {
        int r = m0 + tr * 8 + i;
        if (r < M) {
#pragma unroll
            for (int j = 0; j < TN; j++)
                C[(size_t)r * Nd + n0 + tc * TN + j] = (_Float16)acc[i][j];
        }
    }
}

// ---------------- per-(node,head) attention dots (fp16 input, half8 loads) ----------------

template <int H, int C>
__global__ void attn_dots_h_kernel(const _Float16* __restrict__ hin,
                                   const float* __restrict__ as_, const float* __restrict__ ad_,
                                   float* __restrict__ es, float* __restrict__ ed) {
    int t = blockIdx.x * blockDim.x + threadIdx.x;
    if (t >= N_NODES * H) return;
    int n = t / H, hh = t % H;
    const half8* row = (const half8*)(hin + (size_t)n * (H * C) + hh * C);
    float s1 = 0.f, s2 = 0.f;
#pragma unroll
    for (int c8 = 0; c8 < C / 8; c8++) {
        half8 v = row[c8];
#pragma unroll
        for (int j = 0; j < 8; j++) {
            float f = (float)v[j];
            s1 += f * as_[hh * C + c8 * 8 + j];
            s2 += f * ad_[hh * C + c8 * 8 + j];
        }
    }
    es[t] = s1;
    ed[t] = s2;
}

// ---------------- per-dst online-softmax + fp16 group-gather + bias/BN/ELU ----------------
// RT = HC/8 threads cover one row (half8 16B/thread); G = BLK/RT edge groups.

template <int H, int C>
__global__ __launch_bounds__((H * C < 64) ? 64 : H * C) void gat_agg_h_kernel(
        const _Float16* __restrict__ hin,
        const int* __restrict__ rp, const int* __restrict__ col,
        const float* __restrict__ es, const float* __restrict__ ed,
        const float* __restrict__ bias, const float* __restrict__ gg,
        const float* __restrict__ bb,
        float* __restrict__ out) {
    constexpr int HC  = H * C;
    constexpr int BLK = (HC < 64) ? 64 : HC;
    constexpr int LPH = (BLK / H > 64) ? 64 : (BLK / H);
    constexpr int RT  = HC / 8;    // threads per row (16B/thread)
    constexpr int G   = BLK / RT;  // concurrent edge groups
    constexpr int CH  = 64;
    __shared__ int   s_src[CH];
    __shared__ float s_w[H][CH];
    __shared__ float s_red[G][HC];
    __shared__ float s_m[H], s_den[H], s_scale[H], s_ed[H];

    int n = blockIdx.x;
    int tid = threadIdx.x;
    int start = rp[n], end = rp[n + 1];
    if (tid < H) {
        s_m[tid] = -INFINITY;
        s_den[tid] = 0.f;
        s_ed[tid] = ed[(size_t)n * H + tid];
    }
    __syncthreads();

    int ghh = tid / LPH, glane = tid % LPH;
    int g = tid / RT, rl = tid % RT;
    int hh2 = (rl * 8) / C;        // head owning my 8 channels
    float a0[8], a1[8];
#pragma unroll
    for (int j = 0; j < 8; j++) { a0[j] = 0.f; a1[j] = 0.f; }

    for (int cs = start; cs < end; cs += CH) {
        int cnt = min(CH, end - cs);
        if (tid < cnt) s_src[tid] = col[cs + tid];
        __syncthreads();

        // ---- softmax bookkeeping (LPH lanes per head) ----
        {
            float lmax = -INFINITY;
            for (int e = glane; e < cnt; e += LPH) {
                float l = es[(size_t)s_src[e] * H + ghh] + s_ed[ghh];
                l = (l > 0.f) ? l : 0.2f * l;
                s_w[ghh][e] = l;
                lmax = fmaxf(lmax, l);
            }
#pragma unroll
            for (int off = LPH >> 1; off > 0; off >>= 1)
                lmax = fmaxf(lmax, __shfl_xor(lmax, off));
            float mold = s_m[ghh];
            float nm = fmaxf(mold, lmax);
            float fac = __expf(mold - nm);
            float psum = 0.f;
            for (int e = glane; e < cnt; e += LPH) {
                float w = __expf(s_w[ghh][e] - nm);
                s_w[ghh][e] = w;
                psum += w;
            }
#pragma unroll
            for (int off = LPH >> 1; off > 0; off >>= 1)
                psum += __shfl_xor(psum, off);
            if (glane == 0) {
                s_den[ghh] = s_den[ghh] * fac + psum;
                s_m[ghh] = nm;
                s_scale[ghh] = fac;
            }
        }
        __syncthreads();

        // ---- half8 gather, G edges concurrently, 2-deep unroll ----
        {
            float fac = s_scale[hh2];
#pragma unroll
            for (int j = 0; j < 8; j++) a0[j] *= fac;
            int e = g;
            for (; e + G < cnt; e += 2 * G) {
                float w0 = s_w[hh2][e];
                float w1 = s_w[hh2][e + G];
                half8 v0 = *(const half8*)&hin[(size_t)s_src[e] * HC + rl * 8];
                half8 v1 = *(const half8*)&hin[(size_t)s_src[e + G] * HC + rl * 8];
#pragma unroll
                for (int j = 0; j < 8; j++) a0[j] += w0 * (float)v0[j];
#pragma unroll
                for (int j = 0; j < 8; j++) a1[j] += w1 * (float)v1[j];
            }
            if (e < cnt) {
                float w0 = s_w[hh2][e];
                half8 v0 = *(const half8*)&hin[(size_t)s_src[e] * HC + rl * 8];
#pragma unroll
                for (int j = 0; j < 8; j++) a0[j] += w0 * (float)v0[j];
            }
        }
        __syncthreads();
    }

    // ---- cross-group reduce + epilogue ----
#pragma unroll
    for (int j = 0; j < 8; j++) s_red[g][rl * 8 + j] = a0[j] + a1[j];
    __syncthreads();
    if (tid < HC) {
        int hh = tid / C;
        float res = 0.f;
#pragma unroll
        for (int q = 0; q < G; q++) res += s_red[q][tid];
        res /= s_den[hh];
        res += bias[tid];
        res = res * (gg[tid] / sqrtf(1.00001f)) + bb[tid];
        res = (res > 0.f) ? res : expm1f(res);
        out[(size_t)n * HC + tid] = res;
    }
}

// ---------------- final linear head [N,32] @ [32,1] + bh ----------------

__global__ void head_kernel(const float* __restrict__ h3, const float* __restrict__ Wh,
                            const float* __restrict__ bh, float* __restrict__ out) {
    int n = blockIdx.x * blockDim.x + threadIdx.x;
    if (n < N_NODES) {
        float s = bh[0];
        const float* row = h3 + (size_t)n * 32;
#pragma unroll
        for (int c = 0; c < 32; c++) s += row[c] * Wh[c];
        out[n] = s;
    }
}

// ---------------- launch ----------------

extern "C" void kernel_launch(void* const* d_in, const int* in_sizes, int n_in,
                              void* d_out, int out_size, void* d_ws, size_t ws_size,
                              hipStream_t stream) {
    const float* x   = (const float*)d_in[0];
    const int*   ei  = (const int*)d_in[1];
    const float* W1  = (const float*)d_in[2];
    const float* a1s = (const float*)d_in[3];
    const float* a1d = (const float*)d_in[4];
    const float* b1  = (const float*)d_in[5];
    const float* W2  = (const float*)d_in[6];
    const float* a2s = (const float*)d_in[7];
    const float* a2d = (const float*)d_in[8];
    const float* b2  = (const float*)d_in[9];
    const float* W3  = (const float*)d_in[10];
    const float* a3s = (const float*)d_in[11];
    const float* a3d = (const float*)d_in[12];
    const float* b3  = (const float*)d_in[13];
    const float* g1  = (const float*)d_in[14];
    const float* be1 = (const float*)d_in[15];
    const float* g2  = (const float*)d_in[16];
    const float* be2 = (const float*)d_in[17];
    const float* g3  = (const float*)d_in[18];
    const float* be3 = (const float*)d_in[19];
    const float* Wh  = (const float*)d_in[20];
    const float* bh  = (const float*)d_in[21];
    float* out = (float*)d_out;

    char* ws = (char*)d_ws;
    size_t off = 0;
    auto alloc = [&](size_t bytes) -> void* {
        void* p = ws + off;
        off += (bytes + 255) & ~(size_t)255;
        return p;
    };
    int*   row_ptr = (int*)alloc((N_NODES + 1) * sizeof(int));
    int*   cursor  = (int*)alloc((N_NODES + 1) * sizeof(int));
    int*   bsum    = (int*)alloc(256 * sizeof(int));
    int*   col_src = (int*)alloc((size_t)ET * sizeof(int));
    float* es      = (float*)alloc((size_t)N_NODES * 8 * sizeof(float));
    float* ed      = (float*)alloc((size_t)N_NODES * 8 * sizeof(float));
    float* bufA    = (float*)alloc((size_t)N_NODES * 128 * sizeof(float));  // aggx / agg3-out
    float* bufB    = (float*)alloc((size_t)N_NODES * 128 * sizeof(float));  // h2' post-agg (fp32)
    _Float16* h2h  = (_Float16*)alloc((size_t)N_NODES * 128 * sizeof(_Float16));  // h2 fp16
    _Float16* h3h  = (_Float16*)alloc((size_t)N_NODES * 32 * sizeof(_Float16));   // h3 fp16
    __hip_bfloat16* Ah   = (__hip_bfloat16*)alloc((size_t)MPAD * 512 * sizeof(__hip_bfloat16));
    __hip_bfloat16* Al   = (__hip_bfloat16*)alloc((size_t)MPAD * 512 * sizeof(__hip_bfloat16));
    __hip_bfloat16* W2Th = (__hip_bfloat16*)alloc((size_t)128 * 512 * sizeof(__hip_bfloat16));
    __hip_bfloat16* W2Tl = (__hip_bfloat16*)alloc((size_t)128 * 512 * sizeof(__hip_bfloat16));
    float* M1 = (float*)(ws + ((ws_size - 1024) & ~(size_t)255));
    float* aggx = bufA;   // [N,72] — bufA dead until agg3 output

    // ---- CSR build (dst-sorted), shared by all three layers ----
    zero_int_kernel<<<(N_NODES + 1 + 255) / 256, 256, 0, stream>>>(cursor, N_NODES + 1);
    hist_kernel<<<(ET + 255) / 256, 256, 0, stream>>>(ei, cursor);
    scan1_kernel<<<NBLK_SCAN, 256, 0, stream>>>(cursor, row_ptr, bsum);
    scan2_kernel<<<1, 256, 0, stream>>>(bsum, NBLK_SCAN);
    scan3_kernel<<<NBLK_SCAN, 256, 0, stream>>>(row_ptr, bsum, cursor);
    fill_kernel<<<(ET + 255) / 256, 256, 0, stream>>>(ei, cursor, col_src);

    // ---- layer 1: GAT(9 -> 8x64, concat) + BN + ELU, aggregated in x-space ----
    prep_attn1_kernel<<<1, 256, 0, stream>>>(W1, a1s, a1d, M1);
    es_ed1_kernel<<<(N_NODES + 255) / 256, 256, 0, stream>>>(x, M1, es, ed);
    agg1_kernel<<<N_NODES, 128, 0, stream>>>(x, row_ptr, col_src, es, ed, aggx);
    transform1_kernel<<<(N_NODES + NPB_T1 - 1) / NPB_T1, 256, 0, stream>>>(aggx, W1, b1, g1, be1, Ah, Al);

    // ---- layer 2: GAT(512 -> 4x32, concat) + BN + ELU ----
    prep_w2_kernel<<<256, 256, 0, stream>>>(W2, W2Th, W2Tl);
    gemm2_mfma_kernel<<<MPAD / 128, 256, 0, stream>>>(Ah, Al, W2Th, W2Tl, h2h);
    attn_dots_h_kernel<4, 32><<<(N_NODES * 4 + 255) / 256, 256, 0, stream>>>(h2h, a2s, a2d, es, ed);
    gat_agg_h_kernel<4, 32><<<N_NODES, 128, 0, stream>>>(h2h, row_ptr, col_src, es, ed,
                                                         b2, g2, be2, bufB);

    // ---- layer 3: GAT(128 -> 1x32, mean) + BN + ELU ----
    gemm_h_kernel<1><<<dim3((N_NODES + 63) / 64, 1), 256, 0, stream>>>(bufB, W3, h3h, N_NODES, 128, 32);
    attn_dots_h_kernel<1, 32><<<(N_NODES + 255) / 256, 256, 0, stream>>>(h3h, a3s, a3d, es, ed);
    gat_agg_h_kernel<1, 32><<<N_NODES, 64, 0, stream>>>(h3h, row_ptr, col_src, es, ed,
                                                        b3, g3, be3, bufA);

    // ---- head ----
    head_kernel<<<(N_NODES + 255) / 256, 256, 0, stream>>>(bufA, Wh, bh, out);
}

// Round 7
// 410.996 us; speedup vs baseline: 2.3032x; 1.0507x over previous
//
#include <hip/hip_runtime.h>
#include <hip/hip_bf16.h>
#include <math.h>

#define N_NODES 50000
#define E_EDGES 800000
#define ET (E_EDGES + N_NODES)   // edges + self loops = 850000
#define NBLK_SCAN ((N_NODES + 255) / 256)   // 196
#define MPAD 50048               // 391 * 128
#define NPB_T1 16                // nodes per block in transform1

typedef __attribute__((ext_vector_type(8))) short bf16x8;
typedef __attribute__((ext_vector_type(4))) float f32x4;
typedef __attribute__((ext_vector_type(8))) _Float16 half8;

// ---------------- CSR build ----------------

__global__ void zero_int_kernel(int* __restrict__ p, int n) {
    int i = blockIdx.x * blockDim.x + threadIdx.x;
    if (i < n) p[i] = 0;
}

__global__ void hist_kernel(const int* __restrict__ ei, int* __restrict__ cnt) {
    int e = blockIdx.x * blockDim.x + threadIdx.x;
    if (e < ET) {
        int d = (e < E_EDGES) ? ei[E_EDGES + e] : (e - E_EDGES);
        atomicAdd(&cnt[d], 1);
    }
}

__global__ void scan1_kernel(const int* __restrict__ cnt, int* __restrict__ rp,
                             int* __restrict__ bsum) {
    __shared__ int s[256];
    int i = blockIdx.x * 256 + threadIdx.x;
    int v = (i < N_NODES) ? cnt[i] : 0;
    s[threadIdx.x] = v;
    __syncthreads();
    for (int off = 1; off < 256; off <<= 1) {
        int t = (threadIdx.x >= off) ? s[threadIdx.x - off] : 0;
        __syncthreads();
        s[threadIdx.x] += t;
        __syncthreads();
    }
    if (i < N_NODES) rp[i + 1] = s[threadIdx.x];
    if (threadIdx.x == 255) bsum[blockIdx.x] = s[255];
}

__global__ void scan2_kernel(int* __restrict__ bsum, int nb) {
    __shared__ int s[256];
    int v = (threadIdx.x < nb) ? bsum[threadIdx.x] : 0;
    s[threadIdx.x] = v;
    __syncthreads();
    for (int off = 1; off < 256; off <<= 1) {
        int t = (threadIdx.x >= off) ? s[threadIdx.x - off] : 0;
        __syncthreads();
        s[threadIdx.x] += t;
        __syncthreads();
    }
    if (threadIdx.x < nb) bsum[threadIdx.x] = (threadIdx.x == 0) ? 0 : s[threadIdx.x - 1];
}

__global__ void scan3_kernel(int* __restrict__ rp, const int* __restrict__ bsum,
                             int* __restrict__ cursor) {
    int i = blockIdx.x * 256 + threadIdx.x;
    if (i == 0) rp[0] = 0;
    if (i < N_NODES) {
        int incl = rp[i + 1] + bsum[i >> 8];
        rp[i + 1] = incl;
        cursor[i] = incl - cursor[i];
    }
}

__global__ void fill_kernel(const int* __restrict__ ei, int* __restrict__ cursor,
                            int* __restrict__ col) {
    int e = blockIdx.x * blockDim.x + threadIdx.x;
    if (e < ET) {
        int s_, d;
        if (e < E_EDGES) { s_ = ei[e]; d = ei[E_EDGES + e]; }
        else             { s_ = e - E_EDGES; d = s_; }
        int p = atomicAdd(&cursor[d], 1);
        col[p] = s_;
    }
}

// ---------------- layer-1 specialized path (aggregate in x-space, K=9) ----------------

__global__ void prep_attn1_kernel(const float* __restrict__ W1,
                                  const float* __restrict__ a1s,
                                  const float* __restrict__ a1d,
                                  float* __restrict__ M) {
    int t = threadIdx.x;
    if (t < 144) {
        int which = t / 72, idx = t % 72, k = idx / 8, h = idx % 8;
        const float* a = which ? a1d : a1s;
        float s = 0.f;
        for (int c = 0; c < 64; c++) s += W1[k * 512 + h * 64 + c] * a[h * 64 + c];
        M[t] = s;
    }
}

__global__ void es_ed1_kernel(const float* __restrict__ x, const float* __restrict__ M,
                              float* __restrict__ es, float* __restrict__ ed) {
    int n = blockIdx.x * blockDim.x + threadIdx.x;
    if (n >= N_NODES) return;
    float xr[9];
#pragma unroll
    for (int k = 0; k < 9; k++) xr[k] = x[(size_t)n * 9 + k];
#pragma unroll
    for (int h = 0; h < 8; h++) {
        float s1 = 0.f, s2 = 0.f;
#pragma unroll
        for (int k = 0; k < 9; k++) {
            s1 += xr[k] * M[k * 8 + h];
            s2 += xr[k] * M[72 + k * 8 + h];
        }
        es[(size_t)n * 8 + h] = s1;
        ed[(size_t)n * 8 + h] = s2;
    }
}

// per-dst: online softmax over in-edges + aggregate x rows (9 floats) per head.
__global__ __launch_bounds__(128) void agg1_kernel(const float* __restrict__ x,
        const int* __restrict__ rp, const int* __restrict__ col,
        const float* __restrict__ es, const float* __restrict__ ed,
        float* __restrict__ aggx) {
    __shared__ int   s_src[64];
    __shared__ float s_x[64][9];
    __shared__ float s_es[64][8];
    __shared__ float s_w[8][64];
    __shared__ float s_m[8], s_den[8], s_scale[8], s_ed[8];
    int n = blockIdx.x, tid = threadIdx.x;
    int start = rp[n], end = rp[n + 1];
    if (tid < 8) { s_m[tid] = -INFINITY; s_den[tid] = 0.f; s_ed[tid] = ed[(size_t)n * 8 + tid]; }
    __syncthreads();
    float acc = 0.f;
    int ghh = tid >> 4, glane = tid & 15;
    for (int cs = start; cs < end; cs += 64) {
        int cnt = min(64, end - cs);
        if (tid < cnt) s_src[tid] = col[cs + tid];
        __syncthreads();
        for (int q = tid; q < cnt * 9; q += 128) {
            int e = q / 9, k = q - e * 9;
            s_x[e][k] = x[(size_t)s_src[e] * 9 + k];
        }
        for (int q = tid; q < cnt * 8; q += 128) {
            int e = q >> 3, h = q & 7;
            s_es[e][h] = es[(size_t)s_src[e] * 8 + h];
        }
        __syncthreads();
        float lmax = -INFINITY;
        for (int e = glane; e < cnt; e += 16) {
            float l = s_es[e][ghh] + s_ed[ghh];
            l = (l > 0.f) ? l : 0.2f * l;
            s_w[ghh][e] = l;
            lmax = fmaxf(lmax, l);
        }
#pragma unroll
        for (int off = 8; off > 0; off >>= 1) lmax = fmaxf(lmax, __shfl_xor(lmax, off));
        float mold = s_m[ghh];
        float nm = fmaxf(mold, lmax);
        float fac = __expf(mold - nm);
        float psum = 0.f;
        for (int e = glane; e < cnt; e += 16) {
            float w = __expf(s_w[ghh][e] - nm);
            s_w[ghh][e] = w;
            psum += w;
        }
#pragma unroll
        for (int off = 8; off > 0; off >>= 1) psum += __shfl_xor(psum, off);
        if (glane == 0) { s_den[ghh] = s_den[ghh] * fac + psum; s_m[ghh] = nm; s_scale[ghh] = fac; }
        __syncthreads();
        if (tid < 72) {
            int hh = tid / 9, k = tid - hh * 9;
            float a = acc * s_scale[hh];
            for (int e = 0; e < cnt; e++) a += s_w[hh][e] * s_x[e][k];
            acc = a;
        }
        __syncthreads();
    }
    if (tid < 72) {
        int hh = tid / 9;
        aggx[(size_t)n * 72 + tid] = acc / s_den[hh];
    }
}

// out = ELU(BN( aggx@W1 + b1 )) -> bf16 hi/lo split [MPAD,512].
__global__ __launch_bounds__(256) void transform1_kernel(const float* __restrict__ aggx,
        const float* __restrict__ W1, const float* __restrict__ b1,
        const float* __restrict__ g1, const float* __restrict__ be1,
        __hip_bfloat16* __restrict__ Ah, __hip_bfloat16* __restrict__ Al) {
    __shared__ float s_a[NPB_T1 * 72];
    int tid = threadIdx.x;
    int n0 = blockIdx.x * NPB_T1;
    int nn = min(NPB_T1, N_NODES - n0);
    for (int q = tid; q < nn * 72; q += 256) s_a[q] = aggx[(size_t)n0 * 72 + q];
    int c0 = tid * 2;
    int hh = c0 >> 6;
    float2 wv[9];
#pragma unroll
    for (int k = 0; k < 9; k++) wv[k] = *(const float2*)&W1[k * 512 + c0];
    float2 bv = *(const float2*)&b1[c0];
    float2 gv = *(const float2*)&g1[c0];
    float2 ev = *(const float2*)&be1[c0];
    float gs0 = gv.x / sqrtf(1.00001f), gs1 = gv.y / sqrtf(1.00001f);
    __syncthreads();
    for (int i = 0; i < nn; i++) {
        const float* ar = &s_a[i * 72 + hh * 9];
        float v0 = bv.x, v1 = bv.y;
#pragma unroll
        for (int k = 0; k < 9; k++) { float a = ar[k]; v0 += a * wv[k].x; v1 += a * wv[k].y; }
        v0 = v0 * gs0 + ev.x;
        v1 = v1 * gs1 + ev.y;
        v0 = (v0 > 0.f) ? v0 : expm1f(v0);
        v1 = (v1 > 0.f) ? v1 : expm1f(v1);
        __hip_bfloat16 h0 = __float2bfloat16(v0), h1 = __float2bfloat16(v1);
        float r0 = v0 - __bfloat162float(h0), r1 = v1 - __bfloat162float(h1);
        size_t base = (size_t)(n0 + i) * 512 + c0;
        __hip_bfloat162 hp; hp.x = h0; hp.y = h1;
        __hip_bfloat162 lp; lp.x = __float2bfloat16(r0); lp.y = __float2bfloat16(r1);
        *(__hip_bfloat162*)&Ah[base] = hp;
        *(__hip_bfloat162*)&Al[base] = lp;
    }
}

// W2 [512][128] fp32 -> W2^T hi/lo [128][512] bf16
__global__ void prep_w2_kernel(const float* __restrict__ W2,
                               __hip_bfloat16* __restrict__ Wh,
                               __hip_bfloat16* __restrict__ Wl) {
    int t = blockIdx.x * 256 + threadIdx.x;
    if (t < 512 * 128) {
        int k = t >> 7, c = t & 127;
        float v = W2[t];
        __hip_bfloat16 hi = __float2bfloat16(v);
        float r = v - __bfloat162float(hi);
        Wh[c * 512 + k] = hi;
        Wl[c * 512 + k] = __float2bfloat16(r);
    }
}

// ---------------- layer-2 GEMM via MFMA: h2[N,128] (fp16) = A[N,512] @ W2 ----------------

__global__ __launch_bounds__(256) void gemm2_mfma_kernel(
        const __hip_bfloat16* __restrict__ Ah, const __hip_bfloat16* __restrict__ Al,
        const __hip_bfloat16* __restrict__ Wh, const __hip_bfloat16* __restrict__ Wl,
        _Float16* __restrict__ C) {
    __shared__ short lds[32768];   // 64 KB: Ah | Al | Wh | Wl, 8192 shorts each
    int tid = threadIdx.x;
    int wv = tid >> 6;
    int lane = tid & 63;
    int lrow = lane & 15, kgrp = lane >> 4;
    int m0 = blockIdx.x * 128;

    f32x4 acc[2][8];
#pragma unroll
    for (int m = 0; m < 2; m++)
#pragma unroll
        for (int n = 0; n < 8; n++) acc[m][n] = (f32x4){0.f, 0.f, 0.f, 0.f};

    for (int kk = 0; kk < 512; kk += 64) {
#pragma unroll
        for (int tI = 0; tI < 4; tI++) {
            const __hip_bfloat16* src = (tI == 0) ? Ah : (tI == 1) ? Al : (tI == 2) ? Wh : Wl;
            int rowBase = (tI < 2) ? m0 : 0;
#pragma unroll
            for (int i = 0; i < 4; i++) {
                int gid = tid + 256 * i;
                int row = gid >> 3, kg = gid & 7;
                bf16x8 v = *(const bf16x8*)(src + (size_t)(rowBase + row) * 512 + kk + kg * 8);
                *(bf16x8*)(lds + tI * 8192 + row * 64 + ((kg ^ (row & 7)) << 3)) = v;
            }
        }
        __syncthreads();
#pragma unroll
        for (int ks = 0; ks < 2; ks++) {
            bf16x8 ah[2], al[2];
#pragma unroll
            for (int m = 0; m < 2; m++) {
                int row = wv * 32 + m * 16 + lrow;
                int kg = ks * 4 + kgrp;
                int so = row * 64 + ((kg ^ (row & 7)) << 3);
                ah[m] = *(const bf16x8*)(lds + so);
                al[m] = *(const bf16x8*)(lds + 8192 + so);
            }
#pragma unroll
            for (int n = 0; n < 8; n++) {
                int colr = n * 16 + lrow;
                int kg = ks * 4 + kgrp;
                int so = colr * 64 + ((kg ^ (colr & 7)) << 3);
                bf16x8 wh = *(const bf16x8*)(lds + 16384 + so);
                bf16x8 wl = *(const bf16x8*)(lds + 24576 + so);
#pragma unroll
                for (int m = 0; m < 2; m++) {
                    acc[m][n] = __builtin_amdgcn_mfma_f32_16x16x32_bf16(ah[m], wh, acc[m][n], 0, 0, 0);
                    acc[m][n] = __builtin_amdgcn_mfma_f32_16x16x32_bf16(al[m], wh, acc[m][n], 0, 0, 0);
                    acc[m][n] = __builtin_amdgcn_mfma_f32_16x16x32_bf16(ah[m], wl, acc[m][n], 0, 0, 0);
                }
            }
        }
        __syncthreads();
    }
#pragma unroll
    for (int m = 0; m < 2; m++) {
#pragma unroll
        for (int n = 0; n < 8; n++) {
#pragma unroll
            for (int r = 0; r < 4; r++) {
                int row = m0 + wv * 32 + m * 16 + (lane >> 4) * 4 + r;
                int colc = n * 16 + (lane & 15);
                if (row < N_NODES) C[(size_t)row * 128 + colc] = (_Float16)acc[m][n][r];
            }
        }
    }
}

// ---------------- per-(node,head) attention dots (fp16 input, half8 loads) ----------------

template <int H, int C>
__global__ void attn_dots_h_kernel(const _Float16* __restrict__ hin,
                                   const float* __restrict__ as_, const float* __restrict__ ad_,
                                   float* __restrict__ es, float* __restrict__ ed) {
    int t = blockIdx.x * blockDim.x + threadIdx.x;
    if (t >= N_NODES * H) return;
    int n = t / H, hh = t % H;
    const half8* row = (const half8*)(hin + (size_t)n * (H * C) + hh * C);
    float s1 = 0.f, s2 = 0.f;
#pragma unroll
    for (int c8 = 0; c8 < C / 8; c8++) {
        half8 v = row[c8];
#pragma unroll
        for (int j = 0; j < 8; j++) {
            float f = (float)v[j];
            s1 += f * as_[hh * C + c8 * 8 + j];
            s2 += f * ad_[hh * C + c8 * 8 + j];
        }
    }
    es[t] = s1;
    ed[t] = s2;
}

// ---------------- layer-2 agg (1 wave) + fused layer-3 GEMM + attn dots ----------------
// 64 threads = 1 wave: __syncthreads compiles to waitcnt (no s_barrier).
// Gather: RT=16 threads/row (half8), G=4 edge groups. Epilogue: h2' row [128]
// in LDS -> h3[n,32] = ELU(BN(row)) @ W3 (L1-hot) -> fp16, + es3/ed3 dots.

__global__ __launch_bounds__(64) void agg2_fused_kernel(
        const _Float16* __restrict__ hin,
        const int* __restrict__ rp, const int* __restrict__ col,
        const float* __restrict__ es, const float* __restrict__ ed,
        const float* __restrict__ b2, const float* __restrict__ g2,
        const float* __restrict__ be2,
        const float* __restrict__ W3, const float* __restrict__ a3s,
        const float* __restrict__ a3d,
        _Float16* __restrict__ h3, float* __restrict__ es3, float* __restrict__ ed3) {
    constexpr int H = 4, HC = 128, LPH = 16, G = 4, CH = 64;
    __shared__ int   s_src[CH];
    __shared__ float s_w[H][CH];
    __shared__ float s_red[G][HC];
    __shared__ float s_res[HC];
    __shared__ float s_m[H], s_den[H], s_scale[H], s_ed[H];

    int n = blockIdx.x, tid = threadIdx.x;
    int start = rp[n], end = rp[n + 1];
    if (tid < H) { s_m[tid] = -INFINITY; s_den[tid] = 0.f; s_ed[tid] = ed[(size_t)n * H + tid]; }
    __syncthreads();

    int ghh = tid >> 4, glane = tid & 15;      // softmax: 16 lanes per head
    int g = tid >> 4, rl = tid & 15;           // gather: group g, row-lane rl
    int hh2 = rl >> 2;                         // head owning channels rl*8..rl*8+7
    float a0[8], a1[8];
#pragma unroll
    for (int j = 0; j < 8; j++) { a0[j] = 0.f; a1[j] = 0.f; }

    for (int cs = start; cs < end; cs += CH) {
        int cnt = min(CH, end - cs);
        if (tid < cnt) s_src[tid] = col[cs + tid];
        __syncthreads();

        {
            float lmax = -INFINITY;
            for (int e = glane; e < cnt; e += LPH) {
                float l = es[(size_t)s_src[e] * H + ghh] + s_ed[ghh];
                l = (l > 0.f) ? l : 0.2f * l;
                s_w[ghh][e] = l;
                lmax = fmaxf(lmax, l);
            }
#pragma unroll
            for (int off = 8; off > 0; off >>= 1) lmax = fmaxf(lmax, __shfl_xor(lmax, off));
            float mold = s_m[ghh];
            float nm = fmaxf(mold, lmax);
            float fac = __expf(mold - nm);
            float psum = 0.f;
            for (int e = glane; e < cnt; e += LPH) {
                float w = __expf(s_w[ghh][e] - nm);
                s_w[ghh][e] = w;
                psum += w;
            }
#pragma unroll
            for (int off = 8; off > 0; off >>= 1) psum += __shfl_xor(psum, off);
            if (glane == 0) { s_den[ghh] = s_den[ghh] * fac + psum; s_m[ghh] = nm; s_scale[ghh] = fac; }
        }
        __syncthreads();

        {
            float fac = s_scale[hh2];
#pragma unroll
            for (int j = 0; j < 8; j++) a0[j] *= fac;
            int e = g;
            for (; e + G < cnt; e += 2 * G) {
                float w0 = s_w[hh2][e];
                float w1 = s_w[hh2][e + G];
                half8 v0 = *(const half8*)&hin[(size_t)s_src[e] * HC + rl * 8];
                half8 v1 = *(const half8*)&hin[(size_t)s_src[e + G] * HC + rl * 8];
#pragma unroll
                for (int j = 0; j < 8; j++) a0[j] += w0 * (float)v0[j];
#pragma unroll
                for (int j = 0; j < 8; j++) a1[j] += w1 * (float)v1[j];
            }
            if (e < cnt) {
                float w0 = s_w[hh2][e];
                half8 v0 = *(const half8*)&hin[(size_t)s_src[e] * HC + rl * 8];
#pragma unroll
                for (int j = 0; j < 8; j++) a0[j] += w0 * (float)v0[j];
            }
        }
        __syncthreads();
    }

#pragma unroll
    for (int j = 0; j < 8; j++) s_red[g][rl * 8 + j] = a0[j] + a1[j];
    __syncthreads();

    // h2' row: 2 channels per thread, BN+ELU into s_res
    const float rsq = 0.99999499f;   // 1/sqrt(1+1e-5)
#pragma unroll
    for (int half = 0; half < 2; half++) {
        int c = tid + half * 64;
        float r = s_red[0][c] + s_red[1][c] + s_red[2][c] + s_red[3][c];
        r /= s_den[c >> 5];
        r += b2[c];
        r = r * (g2[c] * rsq) + be2[c];
        r = (r > 0.f) ? r : expm1f(r);
        s_res[c] = r;
    }
    __syncthreads();

    // h3 = s_res @ W3 ([128][32], L1-hot): lane (j, half) sums 64 terms, pair-reduce
    int halfk = tid >> 5, j = tid & 31;
    float v = 0.f;
#pragma unroll 16
    for (int c = halfk * 64; c < halfk * 64 + 64; c++) v += s_res[c] * W3[c * 32 + j];
    v += __shfl_xor(v, 32);
    if (tid < 32) h3[(size_t)n * 32 + j] = (_Float16)v;
    // es3/ed3 dots over 32 channels (both halves hold identical v per j)
    float p1 = v * a3s[j], p2 = v * a3d[j];
#pragma unroll
    for (int off = 16; off > 0; off >>= 1) {
        p1 += __shfl_xor(p1, off);
        p2 += __shfl_xor(p2, off);
    }
    if (tid == 0) { es3[n] = p1; ed3[n] = p2; }
}

// ---------------- layer-3 agg (1 wave) + fused head ----------------
// H=1, 32 channels: RT=4 threads/row, G=16 groups; out[n] = ELU(BN(agg))·Wh + bh.

__global__ __launch_bounds__(64) void agg3_fused_kernel(
        const _Float16* __restrict__ hin,
        const int* __restrict__ rp, const int* __restrict__ col,
        const float* __restrict__ es3, const float* __restrict__ ed3,
        const float* __restrict__ b3, const float* __restrict__ g3,
        const float* __restrict__ be3,
        const float* __restrict__ Wh, const float* __restrict__ bh,
        float* __restrict__ out) {
    constexpr int G = 16, CH = 64;
    __shared__ int   s_src[CH];
    __shared__ float s_w[CH];
    __shared__ float s_red[G][32];
    __shared__ float s_m1, s_den1, s_scale1, s_ed1;

    int n = blockIdx.x, tid = threadIdx.x;
    int start = rp[n], end = rp[n + 1];
    if (tid == 0) { s_m1 = -INFINITY; s_den1 = 0.f; s_ed1 = ed3[n]; }
    __syncthreads();

    int g = tid >> 2, rl = tid & 3;
    float a0[8], a1[8];
#pragma unroll
    for (int j = 0; j < 8; j++) { a0[j] = 0.f; a1[j] = 0.f; }

    for (int cs = start; cs < end; cs += CH) {
        int cnt = min(CH, end - cs);
        if (tid < cnt) s_src[tid] = col[cs + tid];
        __syncthreads();

        float lmax = -INFINITY;
        float l = 0.f;
        if (tid < cnt) {
            l = es3[s_src[tid]] + s_ed1;
            l = (l > 0.f) ? l : 0.2f * l;
            lmax = l;
        }
#pragma unroll
        for (int off = 32; off > 0; off >>= 1) lmax = fmaxf(lmax, __shfl_xor(lmax, off));
        float mold = s_m1;
        float nm = fmaxf(mold, lmax);
        float fac = __expf(mold - nm);
        float w = 0.f;
        if (tid < cnt) {
            w = __expf(l - nm);
            s_w[tid] = w;
        }
        float psum = w;
#pragma unroll
        for (int off = 32; off > 0; off >>= 1) psum += __shfl_xor(psum, off);
        if (tid == 0) { s_den1 = s_den1 * fac + psum; s_m1 = nm; s_scale1 = fac; }
        __syncthreads();

        {
#pragma unroll
            for (int j = 0; j < 8; j++) a0[j] *= fac;
            int e = g;
            for (; e + G < cnt; e += 2 * G) {
                float w0 = s_w[e];
                float w1 = s_w[e + G];
                half8 v0 = *(const half8*)&hin[(size_t)s_src[e] * 32 + rl * 8];
                half8 v1 = *(const half8*)&hin[(size_t)s_src[e + G] * 32 + rl * 8];
#pragma unroll
                for (int j = 0; j < 8; j++) a0[j] += w0 * (float)v0[j];
#pragma unroll
                for (int j = 0; j < 8; j++) a1[j] += w1 * (float)v1[j];
            }
            if (e < cnt) {
                float w0 = s_w[e];
                half8 v0 = *(const half8*)&hin[(size_t)s_src[e] * 32 + rl * 8];
#pragma unroll
                for (int j = 0; j < 8; j++) a0[j] += w0 * (float)v0[j];
            }
        }
        __syncthreads();
    }

#pragma unroll
    for (int j = 0; j < 8; j++) s_red[g][rl * 8 + j] = a0[j] + a1[j];
    __syncthreads();

    const float rsq = 0.99999499f;
    float p = 0.f;
    if (tid < 32) {
        float r = 0.f;
#pragma unroll
        for (int q = 0; q < G; q++) r += s_red[q][tid];
        r /= s_den1;
        r += b3[tid];
        r = r * (g3[tid] * rsq) + be3[tid];
        r = (r > 0.f) ? r : expm1f(r);
        p = r * Wh[tid];
    }
#pragma unroll
    for (int off = 16; off > 0; off >>= 1) p += __shfl_xor(p, off);
    if (tid == 0) out[n] = p + bh[0];
}

// ---------------- launch ----------------

extern "C" void kernel_launch(void* const* d_in, const int* in_sizes, int n_in,
                              void* d_out, int out_size, void* d_ws, size_t ws_size,
                              hipStream_t stream) {
    const float* x   = (const float*)d_in[0];
    const int*   ei  = (const int*)d_in[1];
    const float* W1  = (const float*)d_in[2];
    const float* a1s = (const float*)d_in[3];
    const float* a1d = (const float*)d_in[4];
    const float* b1  = (const float*)d_in[5];
    const float* W2  = (const float*)d_in[6];
    const float* a2s = (const float*)d_in[7];
    const float* a2d = (const float*)d_in[8];
    const float* b2  = (const float*)d_in[9];
    const float* W3  = (const float*)d_in[10];
    const float* a3s = (const float*)d_in[11];
    const float* a3d = (const float*)d_in[12];
    const float* b3  = (const float*)d_in[13];
    const float* g1  = (const float*)d_in[14];
    const float* be1 = (const float*)d_in[15];
    const float* g2  = (const float*)d_in[16];
    const float* be2 = (const float*)d_in[17];
    const float* g3  = (const float*)d_in[18];
    const float* be3 = (const float*)d_in[19];
    const float* Wh  = (const float*)d_in[20];
    const float* bh  = (const float*)d_in[21];
    float* out = (float*)d_out;

    char* ws = (char*)d_ws;
    size_t off = 0;
    auto alloc = [&](size_t bytes) -> void* {
        void* p = ws + off;
        off += (bytes + 255) & ~(size_t)255;
        return p;
    };
    int*   row_ptr = (int*)alloc((N_NODES + 1) * sizeof(int));
    int*   cursor  = (int*)alloc((N_NODES + 1) * sizeof(int));
    int*   bsum    = (int*)alloc(256 * sizeof(int));
    int*   col_src = (int*)alloc((size_t)ET * sizeof(int));
    float* es      = (float*)alloc((size_t)N_NODES * 8 * sizeof(float));
    float* ed      = (float*)alloc((size_t)N_NODES * 8 * sizeof(float));
    float* es3     = (float*)alloc((size_t)N_NODES * sizeof(float));
    float* ed3     = (float*)alloc((size_t)N_NODES * sizeof(float));
    float* bufA    = (float*)alloc((size_t)N_NODES * 72 * sizeof(float));         // aggx
    _Float16* h2h  = (_Float16*)alloc((size_t)N_NODES * 128 * sizeof(_Float16));  // h2 fp16
    _Float16* h3h  = (_Float16*)alloc((size_t)N_NODES * 32 * sizeof(_Float16));   // h3 fp16
    __hip_bfloat16* Ah   = (__hip_bfloat16*)alloc((size_t)MPAD * 512 * sizeof(__hip_bfloat16));
    __hip_bfloat16* Al   = (__hip_bfloat16*)alloc((size_t)MPAD * 512 * sizeof(__hip_bfloat16));
    __hip_bfloat16* W2Th = (__hip_bfloat16*)alloc((size_t)128 * 512 * sizeof(__hip_bfloat16));
    __hip_bfloat16* W2Tl = (__hip_bfloat16*)alloc((size_t)128 * 512 * sizeof(__hip_bfloat16));
    float* M1 = (float*)(ws + ((ws_size - 1024) & ~(size_t)255));
    float* aggx = bufA;

    // ---- CSR build (dst-sorted), shared by all three layers ----
    zero_int_kernel<<<(N_NODES + 1 + 255) / 256, 256, 0, stream>>>(cursor, N_NODES + 1);
    hist_kernel<<<(ET + 255) / 256, 256, 0, stream>>>(ei, cursor);
    scan1_kernel<<<NBLK_SCAN, 256, 0, stream>>>(cursor, row_ptr, bsum);
    scan2_kernel<<<1, 256, 0, stream>>>(bsum, NBLK_SCAN);
    scan3_kernel<<<NBLK_SCAN, 256, 0, stream>>>(row_ptr, bsum, cursor);
    fill_kernel<<<(ET + 255) / 256, 256, 0, stream>>>(ei, cursor, col_src);

    // ---- layer 1: GAT(9 -> 8x64, concat) + BN + ELU, aggregated in x-space ----
    prep_attn1_kernel<<<1, 256, 0, stream>>>(W1, a1s, a1d, M1);
    es_ed1_kernel<<<(N_NODES + 255) / 256, 256, 0, stream>>>(x, M1, es, ed);
    agg1_kernel<<<N_NODES, 128, 0, stream>>>(x, row_ptr, col_src, es, ed, aggx);
    transform1_kernel<<<(N_NODES + NPB_T1 - 1) / NPB_T1, 256, 0, stream>>>(aggx, W1, b1, g1, be1, Ah, Al);

    // ---- layer 2: GAT(512 -> 4x32, concat) + BN + ELU (+ fused layer-3 prep) ----
    prep_w2_kernel<<<256, 256, 0, stream>>>(W2, W2Th, W2Tl);
    gemm2_mfma_kernel<<<MPAD / 128, 256, 0, stream>>>(Ah, Al, W2Th, W2Tl, h2h);
    attn_dots_h_kernel<4, 32><<<(N_NODES * 4 + 255) / 256, 256, 0, stream>>>(h2h, a2s, a2d, es, ed);
    agg2_fused_kernel<<<N_NODES, 64, 0, stream>>>(h2h, row_ptr, col_src, es, ed,
                                                  b2, g2, be2, W3, a3s, a3d,
                                                  h3h, es3, ed3);

    // ---- layer 3 agg + head (fused) ----
    agg3_fused_kernel<<<N_NODES, 64, 0, stream>>>(h3h, row_ptr, col_src, es3, ed3,
                                                  b3, g3, be3, Wh, bh, out);
}